// Round 16
// baseline (367.490 us; speedup 1.0000x reference)
//
#include <hip/hip_runtime.h>
#include <math.h>

#define BN    8
#define NN    2048
#define NP1   2049
#define VSTR  2056   // padded a/b vector stride (floats), 16B-aligned rows
#define DD    256
#define NITER 20
#define NBLK  256    // persistent grid size, 1 block/CU
#define GRP   32     // blocks per batch (independent barrier group)

typedef float f32x2 __attribute__((ext_vector_type(2)));
typedef float f32x4_t __attribute__((ext_vector_type(4)));
typedef short short8 __attribute__((ext_vector_type(8)));

// ws layout: a[BN*VSTR] f32 | b[BN*VSTR] f32 | sums[41*BN] f32 | bar[BN*GRP] i32 |
//            psum[2*BN*GRP] f32 (unused) | K8[BN*NN*NN] fp8 | F16[BN*NN*DD] bf16

__global__ void init_kernel(float* __restrict__ bvec, int nb, float* __restrict__ sums,
                            int* __restrict__ bar) {
    int tid = blockIdx.x * blockDim.x + threadIdx.x;
    int stride = gridDim.x * blockDim.x;
    for (int i = tid; i < nb; i += stride) bvec[i] = 1.0f;            // v0 = 0 -> b = 1
    for (int i = tid; i < 41 * BN; i += stride) sums[i] = (i < BN) ? (float)NN : 0.0f;
    if (tid < BN * GRP) bar[tid] = 0;
}

__device__ __forceinline__ unsigned short f2bf(float f) {
    unsigned u = __builtin_bit_cast(unsigned, f);
    return (unsigned short)((u + 0x7fffu + ((u >> 16) & 1u)) >> 16);   // RNE
}

// Pre-pass: F (B,D,N) f32 -> F16 (B,N,D) bf16, LDS-tiled 64x64 transpose.
// Converts once so build_k3's 16x-re-read pulls half the bytes and no VALU.
__global__ __launch_bounds__(256) void f_to_bf16(const float* __restrict__ F,
                                                 unsigned char* __restrict__ F16) {
    int x0 = blockIdx.x * 64, k0 = blockIdx.y * 64, bb = blockIdx.z;
    __shared__ unsigned short tile[64][68];    // 68-pad: 8B-aligned rows
    int t = threadIdx.x;
    const float* Fb = F + (size_t)bb * DD * NN;
#pragma unroll
    for (int q = 0; q < 16; q++) {
        int idx = q * 256 + t;
        int kk = idx >> 6, xx = idx & 63;
        tile[xx][kk] = f2bf(Fb[(size_t)(k0 + kk) * NN + x0 + xx]);
    }
    __syncthreads();
    int r = t >> 2, c = t & 3;                 // row, 16-elem chunk
    const unsigned long long* src = (const unsigned long long*)&tile[r][c * 16];
    unsigned long long v0 = src[0], v1 = src[1], v2 = src[2], v3 = src[3];
    unsigned char* dst = F16 + (((size_t)bb * NN + x0 + r) * DD + k0) * 2 + c * 32;
    ((unsigned long long*)dst)[0] = v0;
    ((unsigned long long*)dst)[1] = v1;
    ((unsigned long long*)dst)[2] = v2;
    ((unsigned long long*)dst)[3] = v3;
}

// build_k v3b: MFMA bf16 from pre-converted F16 (x-major). K = exp(F^T F / 16),
// diag=0, fp8 out. 128x128 tile, 4 waves (2x2), 4x4 frags of 16x16x32_bf16.
// Staging = pure uint4 copies (no conversion). Epilogue unchanged from R15.
__global__ __launch_bounds__(256) void build_k3(const unsigned char* __restrict__ F16,
                                                unsigned char* __restrict__ K8) {
    int ti = blockIdx.x, tj = blockIdx.y, bb = blockIdx.z;
    int i0 = ti * 128, j0 = tj * 128;
    const unsigned char* F16b = F16 + (size_t)bb * NN * DD * 2;

    __shared__ __align__(16) unsigned char Ab[128 * 80];   // [x][k] bf16, 80B rows
    __shared__ __align__(16) unsigned char Bb[128 * 80];
    __shared__ __align__(4)  unsigned char Cm[128 * 132];  // col-major fp8 [c][i]

    int t = threadIdx.x;
    int w = t >> 6, l = t & 63;
    int wr = w >> 1, wc = w & 1;           // wave grid 2x2 -> 64x64 per wave
    int g = l >> 4, c16 = l & 15;

    f32x4_t acc[4][4];
#pragma unroll
    for (int r = 0; r < 4; r++)
#pragma unroll
        for (int c = 0; c < 4; c++) acc[r][c] = (f32x4_t){0.f, 0.f, 0.f, 0.f};

    int xr = t >> 2, q4 = t & 3;
    for (int k0 = 0; k0 < DD; k0 += 32) {
#pragma unroll
        for (int h = 0; h < 2; h++) {
            int x = h * 64 + xr;
            uint4 va = *(const uint4*)(F16b + ((size_t)(i0 + x) * DD + k0) * 2 + q4 * 16);
            uint4 vb = *(const uint4*)(F16b + ((size_t)(j0 + x) * DD + k0) * 2 + q4 * 16);
            *(uint4*)(Ab + x * 80 + q4 * 16) = va;
            *(uint4*)(Bb + x * 80 + q4 * 16) = vb;
        }
        __syncthreads();

        short8 af[4], bf_[4];
#pragma unroll
        for (int rf = 0; rf < 4; rf++)
            af[rf] = *(const short8*)(Ab + (wr * 64 + rf * 16 + c16) * 80 + g * 16);
#pragma unroll
        for (int cf = 0; cf < 4; cf++)
            bf_[cf] = *(const short8*)(Bb + (wc * 64 + cf * 16 + c16) * 80 + g * 16);
#pragma unroll
        for (int rf = 0; rf < 4; rf++)
#pragma unroll
            for (int cf = 0; cf < 4; cf++)
                acc[rf][cf] = __builtin_amdgcn_mfma_f32_16x16x32_bf16(
                    af[rf], bf_[cf], acc[rf][cf], 0, 0, 0);
        __syncthreads();
    }

#pragma unroll
    for (int rf = 0; rf < 4; rf++) {
#pragma unroll
        for (int cf = 0; cf < 4; cf++) {
            int ib = wr * 64 + rf * 16 + g * 4;
            int jl = wc * 64 + cf * 16 + c16;
            float v[4];
#pragma unroll
            for (int r = 0; r < 4; r++) {
                float e = __expf(acc[rf][cf][r] * 0.0625f);   // 1/sqrt(256)
                if (i0 + ib + r == j0 + jl) e = 0.0f;
                v[r] = e;
            }
            unsigned wd = __builtin_amdgcn_cvt_pk_fp8_f32(v[0], v[1], 0, false);
            wd = __builtin_amdgcn_cvt_pk_fp8_f32(v[2], v[3], wd, true);
            *(unsigned*)(Cm + jl * 132 + ib) = wd;
        }
    }
    __syncthreads();

    unsigned char* K8b = K8 + (size_t)bb * NN * NN;
    int il = t >> 1, hh = t & 1;
    unsigned wrow[16];
#pragma unroll
    for (int cq = 0; cq < 16; cq++) {
        int cb = hh * 64 + cq * 4;
        unsigned b0 = Cm[(cb + 0) * 132 + il];
        unsigned b1 = Cm[(cb + 1) * 132 + il];
        unsigned b2 = Cm[(cb + 2) * 132 + il];
        unsigned b3 = Cm[(cb + 3) * 132 + il];
        wrow[cq] = b0 | (b1 << 8) | (b2 << 16) | (b3 << 24);
    }
    uint4* dst = (uint4*)(K8b + (size_t)(i0 + il) * NN + j0 + hh * 64);
#pragma unroll
    for (int qq = 0; qq < 4; qq++) {
        uint4 u; u.x = wrow[qq * 4]; u.y = wrow[qq * 4 + 1];
        u.z = wrow[qq * 4 + 2]; u.w = wrow[qq * 4 + 3];
        dst[qq] = u;
    }
}

// fp32 fallback build (writes into out, stride NP1). Symmetric-half as before.
__global__ __launch_bounds__(256) void build_k_f32(const float* __restrict__ F,
                                                   float* __restrict__ out) {
    int ti = blockIdx.x, tj = blockIdx.y, bb = blockIdx.z;
    if (tj < ti) return;
    __shared__ float As[32][64];
    __shared__ float Bs[32][64];
    int t  = threadIdx.x;
    int tx = t & 15, ty = t >> 4;
    float acc[4][4] = {};
    const float* Fb = F + (size_t)bb * DD * NN;
    int i0 = ti * 64, j0 = tj * 64;
    for (int k0 = 0; k0 < DD; k0 += 32) {
#pragma unroll
        for (int v = 0; v < 2; v++) {
            int f = t + 256 * v;
            int row = f >> 4, c4 = (f & 15) * 4;
            *(float4*)&As[row][c4] = *(const float4*)&Fb[(size_t)(k0 + row) * NN + i0 + c4];
            *(float4*)&Bs[row][c4] = *(const float4*)&Fb[(size_t)(k0 + row) * NN + j0 + c4];
        }
        __syncthreads();
#pragma unroll
        for (int k = 0; k < 32; k++) {
            float4 av = *(float4*)&As[k][ty * 4];
            float4 bv = *(float4*)&Bs[k][tx * 4];
            float ar[4] = {av.x, av.y, av.z, av.w};
            float br[4] = {bv.x, bv.y, bv.z, bv.w};
#pragma unroll
            for (int r = 0; r < 4; r++)
#pragma unroll
                for (int c = 0; c < 4; c++)
                    acc[r][c] = fmaf(ar[r], br[c], acc[r][c]);
        }
        __syncthreads();
    }
#pragma unroll
    for (int r = 0; r < 4; r++) {
        int i = i0 + ty * 4 + r;
#pragma unroll
        for (int c = 0; c < 4; c++) {
            int j = j0 + tx * 4 + c;
            float Kv = (i == j) ? 0.0f : __expf(acc[r][c] * 0.0625f);
            float* outb = out + (size_t)bb * NP1 * NP1;
            outb[(size_t)i * NP1 + j] = Kv;
            if (tj > ti) outb[(size_t)j * NP1 + i] = Kv;
        }
    }
}

// Persistent Sinkhorn, 128 KB fp8 K-shard in LDS. Fence-free sc1 exchange
// (R15, verified): x values are agent-scope relaxed atomics ordered by
// __syncthreads()'s vmcnt(0) drain; S(x) computed locally. Byte-identical R15.
__global__ __launch_bounds__(1024) void sink_persist(const unsigned char* __restrict__ K8,
                                                     float* __restrict__ avec,
                                                     float* __restrict__ bvec,
                                                     int* __restrict__ bar,
                                                     const float* __restrict__ alpha) {
    int blk   = blockIdx.x;
    int batch = blk & 7;           // XCD id under round-robin dispatch
    int rb    = blk >> 3;
    int tid   = threadIdx.x;
    int seg   = tid & 15;
    int row   = tid >> 4;          // row within the 64-row shard
    int grow  = rb * 64 + row;     // global row

    __shared__ __align__(16) unsigned char Ks[64 * 2048];   // 128 KB fp8 shard
    __shared__ float xs[16 * 132];                          // padded x stage
    __shared__ float wsum[16];

    {
        const int4* gsrc = (const int4*)(K8 + ((size_t)batch * NN + (size_t)rb * 64) * NN);
#pragma unroll
        for (int q = 0; q < 8; q++) {
            int idx = q * 1024 + tid;
            int4 v = gsrc[idx];
            int g = idx * 16;
            int r_ = g >> 11, bir = g & 2047;
            *(int4*)&Ks[r_ * 2048 + (bir ^ (((bir >> 7) & 7) << 4))] = v;
        }
    }   // first pass's __syncthreads() covers this staging

    float* av = avec + (size_t)batch * VSTR;
    float* bv = bvec + (size_t)batch * VSTR;
    int*   gbar = bar + batch * GRP;
    float E    = __expf(alpha[0]);
    float binA = 0.f, binB = 1.0f;
    int   ep   = 0;
    const float4* xp4 = (const float4*)(xs + seg * 132);
    const int kbase = row * 2048;
    const int sb    = seg * 128;
    const int sx    = (seg & 7) << 4;

#define MAC16(KI, ACC)                                                          \
    {                                                                           \
        int4 kv = *(const int4*)&Ks[kbase + ((sb + (KI) * 16) ^ sx)];           \
        float4 xa = xp4[(KI) * 4 + 0], xb = xp4[(KI) * 4 + 1];                  \
        float4 xc = xp4[(KI) * 4 + 2], xd = xp4[(KI) * 4 + 3];                  \
        f32x2 p0 = __builtin_amdgcn_cvt_pk_f32_fp8(kv.x, false);                \
        f32x2 p1 = __builtin_amdgcn_cvt_pk_f32_fp8(kv.x, true);                 \
        f32x2 p2 = __builtin_amdgcn_cvt_pk_f32_fp8(kv.y, false);                \
        f32x2 p3 = __builtin_amdgcn_cvt_pk_f32_fp8(kv.y, true);                 \
        f32x2 p4 = __builtin_amdgcn_cvt_pk_f32_fp8(kv.z, false);                \
        f32x2 p5 = __builtin_amdgcn_cvt_pk_f32_fp8(kv.z, true);                 \
        f32x2 p6 = __builtin_amdgcn_cvt_pk_f32_fp8(kv.w, false);                \
        f32x2 p7 = __builtin_amdgcn_cvt_pk_f32_fp8(kv.w, true);                 \
        ACC = fmaf(p0.x, xa.x, ACC); ACC = fmaf(p0.y, xa.y, ACC);               \
        ACC = fmaf(p1.x, xa.z, ACC); ACC = fmaf(p1.y, xa.w, ACC);               \
        ACC = fmaf(p2.x, xb.x, ACC); ACC = fmaf(p2.y, xb.y, ACC);               \
        ACC = fmaf(p3.x, xb.z, ACC); ACC = fmaf(p3.y, xb.w, ACC);               \
        ACC = fmaf(p4.x, xc.x, ACC); ACC = fmaf(p4.y, xc.y, ACC);               \
        ACC = fmaf(p5.x, xc.z, ACC); ACC = fmaf(p5.y, xc.w, ACC);               \
        ACC = fmaf(p6.x, xd.x, ACC); ACC = fmaf(p6.y, xd.y, ACC);               \
        ACC = fmaf(p7.x, xd.z, ACC); ACC = fmaf(p7.y, xd.w, ACC);               \
    }

#define SINK_PASS(XIN, XOUT, BIN_IN, BIN_OUT, LAST)                             \
    {                                                                           \
        float sv;                                                               \
        {   /* stage XIN via sc1 atomic loads (coherence-point reads) */        \
            float v0 = __hip_atomic_load((XIN) + 2 * tid, __ATOMIC_RELAXED,     \
                                         __HIP_MEMORY_SCOPE_AGENT);             \
            float v1 = __hip_atomic_load((XIN) + 2 * tid + 1, __ATOMIC_RELAXED, \
                                         __HIP_MEMORY_SCOPE_AGENT);             \
            int j = tid * 2;                                                    \
            float* d = xs + ((j >> 7) * 132 + (j & 127));                       \
            d[0] = v0; d[1] = v1;                                               \
            sv = v0 + v1;                                                       \
        }                                                                       \
        sv += __shfl_xor(sv, 1);  sv += __shfl_xor(sv, 2);                      \
        sv += __shfl_xor(sv, 4);  sv += __shfl_xor(sv, 8);                      \
        sv += __shfl_xor(sv, 16); sv += __shfl_xor(sv, 32);                     \
        if ((tid & 63) == 0) wsum[tid >> 6] = sv;                               \
        __syncthreads();                                                        \
        float S_cur = 0.f;                                                      \
        _Pragma("unroll")                                                       \
        for (int w2 = 0; w2 < 16; w2++) S_cur += wsum[w2];                      \
        float dot0 = 0.f, dot1 = 0.f;                                           \
        MAC16(0, dot0) MAC16(1, dot1) MAC16(2, dot0) MAC16(3, dot1)             \
        MAC16(4, dot0) MAC16(5, dot1) MAC16(6, dot0) MAC16(7, dot1)             \
        float dot = dot0 + dot1;                                                \
        dot += __shfl_xor(dot, 1);                                              \
        dot += __shfl_xor(dot, 2);                                              \
        dot += __shfl_xor(dot, 4);                                              \
        dot += __shfl_xor(dot, 8);                                              \
        float val = (1.0f / 4096.0f) / (dot + E * (BIN_IN));                    \
        BIN_OUT = 0.5f / (E * (S_cur + (BIN_IN)));                              \
        if ((tid & 15) == 0)                                                    \
            __hip_atomic_store(&(XOUT)[grow], val, __ATOMIC_RELAXED,            \
                               __HIP_MEMORY_SCOPE_AGENT);                       \
        __syncthreads();   /* vmcnt(0) drain: val stores complete (sc1) */      \
        if (!(LAST)) {                                                          \
            ep++;                                                               \
            if (tid == 0)                                                       \
                __hip_atomic_store(&gbar[rb], ep, __ATOMIC_RELAXED,             \
                                   __HIP_MEMORY_SCOPE_AGENT);                   \
            if (tid < GRP) {                                                    \
                while (__hip_atomic_load(&gbar[tid], __ATOMIC_RELAXED,          \
                                         __HIP_MEMORY_SCOPE_AGENT) < ep)        \
                    __builtin_amdgcn_s_sleep(1);                                \
            }                                                                   \
            __syncthreads();                                                    \
        }                                                                       \
    }

    for (int it2 = 0; it2 < NITER; it2++) {
        SINK_PASS(bv, av, binB, binA, false);
        SINK_PASS(av, bv, binA, binB, (it2 == NITER - 1));
    }
#undef SINK_PASS
#undef MAC16

    if (tid == 0) { av[NN] = binA; bv[NN] = binB; }
}

// fp32 fallback pass (K in d_out, stride NP1) for ws-too-small case.
__global__ __launch_bounds__(256) void sink_pass_f32(const float* __restrict__ K,
                                                     const float* __restrict__ xin,
                                                     float* __restrict__ xout,
                                                     const float* __restrict__ sum_in,
                                                     float* __restrict__ sum_out,
                                                     const float* __restrict__ alpha) {
    int bb = blockIdx.y;
    int i0 = blockIdx.x * 16;
    __shared__ float xsl[NN];
    __shared__ float rowa[16];
    const float* xinb = xin + (size_t)bb * VSTR;
    int t = threadIdx.x;
    for (int j = t; j < NN; j += 256) xsl[j] = xinb[j];
    __syncthreads();
    float E  = __expf(alpha[0]);
    float xN = xinb[NN];
    int wave = t >> 6, lane = t & 63;
    const float* Kb = K + (size_t)bb * NP1 * NP1;
    for (int r = wave; r < 16; r += 4) {
        int i = i0 + r;
        const float* rowp = Kb + (size_t)i * NP1;
        float acc = 0.f;
        for (int j = lane; j < NN; j += 64) acc = fmaf(rowp[j], xsl[j], acc);
#pragma unroll
        for (int off = 32; off >= 1; off >>= 1) acc += __shfl_xor(acc, off);
        if (lane == 0) {
            float v = (1.0f / 4096.0f) / (acc + E * xN);
            xout[(size_t)bb * VSTR + i] = v;
            rowa[r] = v;
        }
    }
    __syncthreads();
    if (t == 0) {
        float s = 0.f;
#pragma unroll
        for (int r = 0; r < 16; r++) s += rowa[r];
        atomicAdd(sum_out + bb, s);
        if (blockIdx.x == 0) xout[(size_t)bb * VSTR + NN] = 0.5f / (E * (sum_in[bb] + xN));
    }
}

// out[i,j] = K*a_i*b_j*4096*cost (i,j<N), bins use E. FP8: K from K8; else in-place.
template <bool FP8>
__global__ __launch_bounds__(256) void final_kernel(float* __restrict__ out,
                                                    const unsigned char* __restrict__ K8,
                                                    const float* __restrict__ avec,
                                                    const float* __restrict__ bvec,
                                                    const float* __restrict__ pos,
                                                    const float* __restrict__ alpha) {
    int bb = blockIdx.y;
    int i0 = blockIdx.x * 16;
    __shared__ float as_[16], ys[16], xs2[16];
    int t = threadIdx.x;
    if (t < 16) {
        int i = i0 + t;
        as_[t] = (i < NP1) ? avec[(size_t)bb * VSTR + i] : 0.f;
        if (i < NN) {
            ys[t]  = pos[((size_t)bb * NN + i) * 2 + 0];
            xs2[t] = pos[((size_t)bb * NN + i) * 2 + 1];
        } else {
            ys[t] = 1e9f; xs2[t] = 1e9f;
        }
    }
    __syncthreads();
    float E = __expf(alpha[0]);
    float* outb = out + (size_t)bb * NP1 * NP1;
    const unsigned char* K8b = K8 + (size_t)bb * NN * NN;
    for (int j = t; j < NP1; j += 256) {
        float bj = bvec[(size_t)bb * VSTR + j];
        bool jin = (j < NN);
        float yj = 0.f, xj = 0.f;
        if (jin) {
            yj = pos[((size_t)bb * NN + j) * 2 + 0];
            xj = pos[((size_t)bb * NN + j) * 2 + 1];
        }
#pragma unroll 1
        for (int r = 0; r < 16; r++) {
            int i = i0 + r;
            if (i >= NP1) break;
            size_t idx = (size_t)i * NP1 + j;
            float v;
            if (i < NN && jin) {
                float Kv;
                if constexpr (FP8)
                    Kv = __builtin_amdgcn_cvt_f32_fp8((int)K8b[(size_t)i * NN + j], 0);
                else
                    Kv = outb[idx];
                bool c = (fabsf(ys[r] - yj) <= 0.1f) && (fabsf(xs2[r] - xj) <= 0.1f);
                v = c ? Kv * as_[r] * bj * 4096.0f : 0.0f;
            } else {
                v = E * as_[r] * bj * 4096.0f;
            }
            outb[idx] = v;
        }
    }
}

extern "C" void kernel_launch(void* const* d_in, const int* in_sizes, int n_in,
                              void* d_out, int out_size, void* d_ws, size_t ws_size,
                              hipStream_t stream) {
    const float* F     = (const float*)d_in[0];  // (B, D, N)
    const float* pos   = (const float*)d_in[1];  // (B, N, 2)
    const float* alpha = (const float*)d_in[3];  // (1,)
    float* out = (float*)d_out;
    float* ws  = (float*)d_ws;

    float* avec = ws;
    float* bvec = ws + BN * VSTR;
    float* sums = ws + 2 * BN * VSTR;                 // 41*BN floats (fallback path)
    int*   bar  = (int*)(sums + 41 * BN);             // BN x GRP arrival slots
    float* psum = (float*)(bar + BN * GRP);           // kept for layout stability
    unsigned char* K8  = (unsigned char*)(psum + 2 * BN * GRP);  // 33.5 MB fp8
    unsigned char* F16 = K8 + (size_t)BN * NN * NN;              // 8.4 MB bf16

    size_t need = (size_t)(2 * BN * VSTR + 41 * BN + 3 * BN * GRP) * 4
                + (size_t)BN * NN * NN + (size_t)BN * NN * DD * 2;
    bool fp8 = (ws_size >= need);

    hipLaunchKernelGGL(init_kernel, dim3(64), dim3(256), 0, stream, bvec, BN * VSTR,
                       sums, bar);

    if (fp8) {
        hipLaunchKernelGGL(f_to_bf16, dim3(NN / 64, DD / 64, BN), dim3(256), 0, stream,
                           F, F16);
        hipLaunchKernelGGL(build_k3, dim3(16, 16, BN), dim3(256), 0, stream, F16, K8);
        const unsigned char* Kp = K8;
        float* ap = avec; float* bp = bvec; int* brp = bar;
        const float* alp = alpha;
        void* params[5] = {(void*)&Kp, (void*)&ap, (void*)&bp, (void*)&brp,
                           (void*)&alp};
        hipLaunchCooperativeKernel((const void*)sink_persist, dim3(NBLK), dim3(1024),
                                   params, 0, stream);
        hipLaunchKernelGGL((final_kernel<true>), dim3((NP1 + 15) / 16, BN), dim3(256), 0,
                           stream, out, K8, avec, bvec, pos, alpha);
    } else {
        hipLaunchKernelGGL(build_k_f32, dim3(32, 32, BN), dim3(256), 0, stream, F, out);
        const float* xin = bvec;
        float* xout = avec;
        for (int p = 1; p <= 2 * NITER; p++) {
            hipLaunchKernelGGL(sink_pass_f32, dim3(NN / 16, BN), dim3(256), 0, stream,
                               out, xin, xout, sums + (p - 1) * BN, sums + p * BN, alpha);
            float* tmp = (float*)xin; xin = xout; xout = tmp;
        }
        hipLaunchKernelGGL((final_kernel<false>), dim3((NP1 + 15) / 16, BN), dim3(256), 0,
                           stream, out, K8, avec, bvec, pos, alpha);
    }
}

// Round 17
// 358.293 us; speedup vs baseline: 1.0257x; 1.0257x over previous
//
#include <hip/hip_runtime.h>
#include <math.h>

#define BN    8
#define NN    2048
#define NP1   2049
#define VSTR  2056   // padded a/b vector stride (floats), 16B-aligned rows
#define DD    256
#define NITER 20
#define NBLK  256    // persistent grid size, 1 block/CU
#define GRP   32     // blocks per batch (independent barrier group)

typedef float f32x2 __attribute__((ext_vector_type(2)));
typedef float f32x4_t __attribute__((ext_vector_type(4)));
typedef short short8 __attribute__((ext_vector_type(8)));

// ws layout: a[BN*VSTR] f32 | b[BN*VSTR] f32 | sums[41*BN] f32 | bar[BN*GRP] i32 |
//            psum[2*BN*GRP] f32 (unused) | K8[BN*NN*NN] fp8 | F16[BN*NN*DD] bf16

__global__ void init_kernel(float* __restrict__ bvec, int nb, float* __restrict__ sums,
                            int* __restrict__ bar) {
    int tid = blockIdx.x * blockDim.x + threadIdx.x;
    int stride = gridDim.x * blockDim.x;
    for (int i = tid; i < nb; i += stride) bvec[i] = 1.0f;            // v0 = 0 -> b = 1
    for (int i = tid; i < 41 * BN; i += stride) sums[i] = (i < BN) ? (float)NN : 0.0f;
    if (tid < BN * GRP) bar[tid] = 0;
}

__device__ __forceinline__ unsigned short f2bf(float f) {
    unsigned u = __builtin_bit_cast(unsigned, f);
    return (unsigned short)((u + 0x7fffu + ((u >> 16) & 1u)) >> 16);   // RNE
}

// Pre-pass: F (B,D,N) f32 -> F16 (B,N,D) bf16, LDS-tiled 64x64 transpose.
__global__ __launch_bounds__(256) void f_to_bf16(const float* __restrict__ F,
                                                 unsigned char* __restrict__ F16) {
    int x0 = blockIdx.x * 64, k0 = blockIdx.y * 64, bb = blockIdx.z;
    __shared__ unsigned short tile[64][68];    // 68-pad: 8B-aligned rows
    int t = threadIdx.x;
    const float* Fb = F + (size_t)bb * DD * NN;
#pragma unroll
    for (int q = 0; q < 16; q++) {
        int idx = q * 256 + t;
        int kk = idx >> 6, xx = idx & 63;
        tile[xx][kk] = f2bf(Fb[(size_t)(k0 + kk) * NN + x0 + xx]);
    }
    __syncthreads();
    int r = t >> 2, c = t & 3;                 // row, 16-elem chunk
    const unsigned long long* src = (const unsigned long long*)&tile[r][c * 16];
    unsigned long long v0 = src[0], v1 = src[1], v2 = src[2], v3 = src[3];
    unsigned char* dst = F16 + (((size_t)bb * NN + x0 + r) * DD + k0) * 2 + c * 32;
    ((unsigned long long*)dst)[0] = v0;
    ((unsigned long long*)dst)[1] = v1;
    ((unsigned long long*)dst)[2] = v2;
    ((unsigned long long*)dst)[3] = v3;
}

// build_k v3c: MFMA bf16 from F16 (x-major). R16 post-mortem: build stuck at
// ~100 us (vs ~40 floor) with traffic-halving neutral -> occupancy x latency
// bound (37.4 KB LDS -> 4 blocks/CU; per-step load->sync->compute exposes
// latency). Fixes: (1) LDS UNION — Cm aliases Ab/Bb (only live post-k-loop;
// trailing syncthreads covers the alias), 37.4 -> 20.5 KB; (2) REGISTER
// DOUBLE-BUFFER staging — prefetch next k-step's 4 uint4 during MFMA.
// Layouts, fragment maps, epilogue identical to R15/R16 (verified).
__global__ __launch_bounds__(256) void build_k3(const unsigned char* __restrict__ F16,
                                                unsigned char* __restrict__ K8) {
    int ti = blockIdx.x, tj = blockIdx.y, bb = blockIdx.z;
    int i0 = ti * 128, j0 = tj * 128;
    const unsigned char* F16b = F16 + (size_t)bb * NN * DD * 2;

    __shared__ __align__(16) unsigned char Smem[128 * 80 * 2];   // 20480 B
    unsigned char* Ab = Smem;                    // [x][k] bf16, 80B rows
    unsigned char* Bb = Smem + 128 * 80;
    unsigned char* Cm = Smem;                    // ALIAS: col-major fp8 [c][i], 16896 B

    int t = threadIdx.x;
    int w = t >> 6, l = t & 63;
    int wr = w >> 1, wc = w & 1;           // wave grid 2x2 -> 64x64 per wave
    int g = l >> 4, c16 = l & 15;

    f32x4_t acc[4][4];
#pragma unroll
    for (int r = 0; r < 4; r++)
#pragma unroll
        for (int c = 0; c < 4; c++) acc[r][c] = (f32x4_t){0.f, 0.f, 0.f, 0.f};

    int xr = t >> 2, q4 = t & 3;
    // prefetch k-step 0 into registers
    uint4 va0 = *(const uint4*)(F16b + ((size_t)(i0 + xr) * DD) * 2 + q4 * 16);
    uint4 va1 = *(const uint4*)(F16b + ((size_t)(i0 + 64 + xr) * DD) * 2 + q4 * 16);
    uint4 vb0 = *(const uint4*)(F16b + ((size_t)(j0 + xr) * DD) * 2 + q4 * 16);
    uint4 vb1 = *(const uint4*)(F16b + ((size_t)(j0 + 64 + xr) * DD) * 2 + q4 * 16);

    for (int k0 = 0; k0 < DD; k0 += 32) {
        // write current regs to LDS
        *(uint4*)(Ab + xr * 80 + q4 * 16)        = va0;
        *(uint4*)(Ab + (64 + xr) * 80 + q4 * 16) = va1;
        *(uint4*)(Bb + xr * 80 + q4 * 16)        = vb0;
        *(uint4*)(Bb + (64 + xr) * 80 + q4 * 16) = vb1;
        __syncthreads();

        // prefetch next k-step (overlaps with ds_read + MFMA below)
        if (k0 + 32 < DD) {
            int kn = (k0 + 32) * 2;
            va0 = *(const uint4*)(F16b + (size_t)(i0 + xr) * DD * 2 + kn + q4 * 16);
            va1 = *(const uint4*)(F16b + (size_t)(i0 + 64 + xr) * DD * 2 + kn + q4 * 16);
            vb0 = *(const uint4*)(F16b + (size_t)(j0 + xr) * DD * 2 + kn + q4 * 16);
            vb1 = *(const uint4*)(F16b + (size_t)(j0 + 64 + xr) * DD * 2 + kn + q4 * 16);
        }

        short8 af[4], bf_[4];
#pragma unroll
        for (int rf = 0; rf < 4; rf++)
            af[rf] = *(const short8*)(Ab + (wr * 64 + rf * 16 + c16) * 80 + g * 16);
#pragma unroll
        for (int cf = 0; cf < 4; cf++)
            bf_[cf] = *(const short8*)(Bb + (wc * 64 + cf * 16 + c16) * 80 + g * 16);
#pragma unroll
        for (int rf = 0; rf < 4; rf++)
#pragma unroll
            for (int cf = 0; cf < 4; cf++)
                acc[rf][cf] = __builtin_amdgcn_mfma_f32_16x16x32_bf16(
                    af[rf], bf_[cf], acc[rf][cf], 0, 0, 0);
        __syncthreads();   // all LDS reads done -> safe to overwrite (next step or Cm)
    }

    // epilogue: exp, diag-zero, pack 4 rows (same col) -> u32 -> col-major LDS
    // (Cm aliases Ab/Bb — safe after the loop's trailing barrier)
#pragma unroll
    for (int rf = 0; rf < 4; rf++) {
#pragma unroll
        for (int cf = 0; cf < 4; cf++) {
            int ib = wr * 64 + rf * 16 + g * 4;
            int jl = wc * 64 + cf * 16 + c16;
            float v[4];
#pragma unroll
            for (int r = 0; r < 4; r++) {
                float e = __expf(acc[rf][cf][r] * 0.0625f);   // 1/sqrt(256)
                if (i0 + ib + r == j0 + jl) e = 0.0f;
                v[r] = e;
            }
            unsigned wd = __builtin_amdgcn_cvt_pk_fp8_f32(v[0], v[1], 0, false);
            wd = __builtin_amdgcn_cvt_pk_fp8_f32(v[2], v[3], wd, true);
            *(unsigned*)(Cm + jl * 132 + ib) = wd;
        }
    }
    __syncthreads();

    unsigned char* K8b = K8 + (size_t)bb * NN * NN;
    int il = t >> 1, hh = t & 1;
    unsigned wrow[16];
#pragma unroll
    for (int cq = 0; cq < 16; cq++) {
        int cb = hh * 64 + cq * 4;
        unsigned b0 = Cm[(cb + 0) * 132 + il];
        unsigned b1 = Cm[(cb + 1) * 132 + il];
        unsigned b2 = Cm[(cb + 2) * 132 + il];
        unsigned b3 = Cm[(cb + 3) * 132 + il];
        wrow[cq] = b0 | (b1 << 8) | (b2 << 16) | (b3 << 24);
    }
    uint4* dst = (uint4*)(K8b + (size_t)(i0 + il) * NN + j0 + hh * 64);
#pragma unroll
    for (int qq = 0; qq < 4; qq++) {
        uint4 u; u.x = wrow[qq * 4]; u.y = wrow[qq * 4 + 1];
        u.z = wrow[qq * 4 + 2]; u.w = wrow[qq * 4 + 3];
        dst[qq] = u;
    }
}

// fp32 fallback build (writes into out, stride NP1). Symmetric-half as before.
__global__ __launch_bounds__(256) void build_k_f32(const float* __restrict__ F,
                                                   float* __restrict__ out) {
    int ti = blockIdx.x, tj = blockIdx.y, bb = blockIdx.z;
    if (tj < ti) return;
    __shared__ float As[32][64];
    __shared__ float Bs[32][64];
    int t  = threadIdx.x;
    int tx = t & 15, ty = t >> 4;
    float acc[4][4] = {};
    const float* Fb = F + (size_t)bb * DD * NN;
    int i0 = ti * 64, j0 = tj * 64;
    for (int k0 = 0; k0 < DD; k0 += 32) {
#pragma unroll
        for (int v = 0; v < 2; v++) {
            int f = t + 256 * v;
            int row = f >> 4, c4 = (f & 15) * 4;
            *(float4*)&As[row][c4] = *(const float4*)&Fb[(size_t)(k0 + row) * NN + i0 + c4];
            *(float4*)&Bs[row][c4] = *(const float4*)&Fb[(size_t)(k0 + row) * NN + j0 + c4];
        }
        __syncthreads();
#pragma unroll
        for (int k = 0; k < 32; k++) {
            float4 av = *(float4*)&As[k][ty * 4];
            float4 bv = *(float4*)&Bs[k][tx * 4];
            float ar[4] = {av.x, av.y, av.z, av.w};
            float br[4] = {bv.x, bv.y, bv.z, bv.w};
#pragma unroll
            for (int r = 0; r < 4; r++)
#pragma unroll
                for (int c = 0; c < 4; c++)
                    acc[r][c] = fmaf(ar[r], br[c], acc[r][c]);
        }
        __syncthreads();
    }
#pragma unroll
    for (int r = 0; r < 4; r++) {
        int i = i0 + ty * 4 + r;
#pragma unroll
        for (int c = 0; c < 4; c++) {
            int j = j0 + tx * 4 + c;
            float Kv = (i == j) ? 0.0f : __expf(acc[r][c] * 0.0625f);
            float* outb = out + (size_t)bb * NP1 * NP1;
            outb[(size_t)i * NP1 + j] = Kv;
            if (tj > ti) outb[(size_t)j * NP1 + i] = Kv;
        }
    }
}

// Persistent Sinkhorn, 128 KB fp8 K-shard in LDS. Fence-free sc1 exchange
// (R15, verified): x values are agent-scope relaxed atomics ordered by
// __syncthreads()'s vmcnt(0) drain; S(x) computed locally. Byte-identical R15.
__global__ __launch_bounds__(1024) void sink_persist(const unsigned char* __restrict__ K8,
                                                     float* __restrict__ avec,
                                                     float* __restrict__ bvec,
                                                     int* __restrict__ bar,
                                                     const float* __restrict__ alpha) {
    int blk   = blockIdx.x;
    int batch = blk & 7;           // XCD id under round-robin dispatch
    int rb    = blk >> 3;
    int tid   = threadIdx.x;
    int seg   = tid & 15;
    int row   = tid >> 4;          // row within the 64-row shard
    int grow  = rb * 64 + row;     // global row

    __shared__ __align__(16) unsigned char Ks[64 * 2048];   // 128 KB fp8 shard
    __shared__ float xs[16 * 132];                          // padded x stage
    __shared__ float wsum[16];

    {
        const int4* gsrc = (const int4*)(K8 + ((size_t)batch * NN + (size_t)rb * 64) * NN);
#pragma unroll
        for (int q = 0; q < 8; q++) {
            int idx = q * 1024 + tid;
            int4 v = gsrc[idx];
            int g = idx * 16;
            int r_ = g >> 11, bir = g & 2047;
            *(int4*)&Ks[r_ * 2048 + (bir ^ (((bir >> 7) & 7) << 4))] = v;
        }
    }   // first pass's __syncthreads() covers this staging

    float* av = avec + (size_t)batch * VSTR;
    float* bv = bvec + (size_t)batch * VSTR;
    int*   gbar = bar + batch * GRP;
    float E    = __expf(alpha[0]);
    float binA = 0.f, binB = 1.0f;
    int   ep   = 0;
    const float4* xp4 = (const float4*)(xs + seg * 132);
    const int kbase = row * 2048;
    const int sb    = seg * 128;
    const int sx    = (seg & 7) << 4;

#define MAC16(KI, ACC)                                                          \
    {                                                                           \
        int4 kv = *(const int4*)&Ks[kbase + ((sb + (KI) * 16) ^ sx)];           \
        float4 xa = xp4[(KI) * 4 + 0], xb = xp4[(KI) * 4 + 1];                  \
        float4 xc = xp4[(KI) * 4 + 2], xd = xp4[(KI) * 4 + 3];                  \
        f32x2 p0 = __builtin_amdgcn_cvt_pk_f32_fp8(kv.x, false);                \
        f32x2 p1 = __builtin_amdgcn_cvt_pk_f32_fp8(kv.x, true);                 \
        f32x2 p2 = __builtin_amdgcn_cvt_pk_f32_fp8(kv.y, false);                \
        f32x2 p3 = __builtin_amdgcn_cvt_pk_f32_fp8(kv.y, true);                 \
        f32x2 p4 = __builtin_amdgcn_cvt_pk_f32_fp8(kv.z, false);                \
        f32x2 p5 = __builtin_amdgcn_cvt_pk_f32_fp8(kv.z, true);                 \
        f32x2 p6 = __builtin_amdgcn_cvt_pk_f32_fp8(kv.w, false);                \
        f32x2 p7 = __builtin_amdgcn_cvt_pk_f32_fp8(kv.w, true);                 \
        ACC = fmaf(p0.x, xa.x, ACC); ACC = fmaf(p0.y, xa.y, ACC);               \
        ACC = fmaf(p1.x, xa.z, ACC); ACC = fmaf(p1.y, xa.w, ACC);               \
        ACC = fmaf(p2.x, xb.x, ACC); ACC = fmaf(p2.y, xb.y, ACC);               \
        ACC = fmaf(p3.x, xb.z, ACC); ACC = fmaf(p3.y, xb.w, ACC);               \
        ACC = fmaf(p4.x, xc.x, ACC); ACC = fmaf(p4.y, xc.y, ACC);               \
        ACC = fmaf(p5.x, xc.z, ACC); ACC = fmaf(p5.y, xc.w, ACC);               \
        ACC = fmaf(p6.x, xd.x, ACC); ACC = fmaf(p6.y, xd.y, ACC);               \
        ACC = fmaf(p7.x, xd.z, ACC); ACC = fmaf(p7.y, xd.w, ACC);               \
    }

#define SINK_PASS(XIN, XOUT, BIN_IN, BIN_OUT, LAST)                             \
    {                                                                           \
        float sv;                                                               \
        {   /* stage XIN via sc1 atomic loads (coherence-point reads) */        \
            float v0 = __hip_atomic_load((XIN) + 2 * tid, __ATOMIC_RELAXED,     \
                                         __HIP_MEMORY_SCOPE_AGENT);             \
            float v1 = __hip_atomic_load((XIN) + 2 * tid + 1, __ATOMIC_RELAXED, \
                                         __HIP_MEMORY_SCOPE_AGENT);             \
            int j = tid * 2;                                                    \
            float* d = xs + ((j >> 7) * 132 + (j & 127));                       \
            d[0] = v0; d[1] = v1;                                               \
            sv = v0 + v1;                                                       \
        }                                                                       \
        sv += __shfl_xor(sv, 1);  sv += __shfl_xor(sv, 2);                      \
        sv += __shfl_xor(sv, 4);  sv += __shfl_xor(sv, 8);                      \
        sv += __shfl_xor(sv, 16); sv += __shfl_xor(sv, 32);                     \
        if ((tid & 63) == 0) wsum[tid >> 6] = sv;                               \
        __syncthreads();                                                        \
        float S_cur = 0.f;                                                      \
        _Pragma("unroll")                                                       \
        for (int w2 = 0; w2 < 16; w2++) S_cur += wsum[w2];                      \
        float dot0 = 0.f, dot1 = 0.f;                                           \
        MAC16(0, dot0) MAC16(1, dot1) MAC16(2, dot0) MAC16(3, dot1)             \
        MAC16(4, dot0) MAC16(5, dot1) MAC16(6, dot0) MAC16(7, dot1)             \
        float dot = dot0 + dot1;                                                \
        dot += __shfl_xor(dot, 1);                                              \
        dot += __shfl_xor(dot, 2);                                              \
        dot += __shfl_xor(dot, 4);                                              \
        dot += __shfl_xor(dot, 8);                                              \
        float val = (1.0f / 4096.0f) / (dot + E * (BIN_IN));                    \
        BIN_OUT = 0.5f / (E * (S_cur + (BIN_IN)));                              \
        if ((tid & 15) == 0)                                                    \
            __hip_atomic_store(&(XOUT)[grow], val, __ATOMIC_RELAXED,            \
                               __HIP_MEMORY_SCOPE_AGENT);                       \
        __syncthreads();   /* vmcnt(0) drain: val stores complete (sc1) */      \
        if (!(LAST)) {                                                          \
            ep++;                                                               \
            if (tid == 0)                                                       \
                __hip_atomic_store(&gbar[rb], ep, __ATOMIC_RELAXED,             \
                                   __HIP_MEMORY_SCOPE_AGENT);                   \
            if (tid < GRP) {                                                    \
                while (__hip_atomic_load(&gbar[tid], __ATOMIC_RELAXED,          \
                                         __HIP_MEMORY_SCOPE_AGENT) < ep)        \
                    __builtin_amdgcn_s_sleep(1);                                \
            }                                                                   \
            __syncthreads();                                                    \
        }                                                                       \
    }

    for (int it2 = 0; it2 < NITER; it2++) {
        SINK_PASS(bv, av, binB, binA, false);
        SINK_PASS(av, bv, binA, binB, (it2 == NITER - 1));
    }
#undef SINK_PASS
#undef MAC16

    if (tid == 0) { av[NN] = binA; bv[NN] = binB; }
}

// fp32 fallback pass (K in d_out, stride NP1) for ws-too-small case.
__global__ __launch_bounds__(256) void sink_pass_f32(const float* __restrict__ K,
                                                     const float* __restrict__ xin,
                                                     float* __restrict__ xout,
                                                     const float* __restrict__ sum_in,
                                                     float* __restrict__ sum_out,
                                                     const float* __restrict__ alpha) {
    int bb = blockIdx.y;
    int i0 = blockIdx.x * 16;
    __shared__ float xsl[NN];
    __shared__ float rowa[16];
    const float* xinb = xin + (size_t)bb * VSTR;
    int t = threadIdx.x;
    for (int j = t; j < NN; j += 256) xsl[j] = xinb[j];
    __syncthreads();
    float E  = __expf(alpha[0]);
    float xN = xinb[NN];
    int wave = t >> 6, lane = t & 63;
    const float* Kb = K + (size_t)bb * NP1 * NP1;
    for (int r = wave; r < 16; r += 4) {
        int i = i0 + r;
        const float* rowp = Kb + (size_t)i * NP1;
        float acc = 0.f;
        for (int j = lane; j < NN; j += 64) acc = fmaf(rowp[j], xsl[j], acc);
#pragma unroll
        for (int off = 32; off >= 1; off >>= 1) acc += __shfl_xor(acc, off);
        if (lane == 0) {
            float v = (1.0f / 4096.0f) / (acc + E * xN);
            xout[(size_t)bb * VSTR + i] = v;
            rowa[r] = v;
        }
    }
    __syncthreads();
    if (t == 0) {
        float s = 0.f;
#pragma unroll
        for (int r = 0; r < 16; r++) s += rowa[r];
        atomicAdd(sum_out + bb, s);
        if (blockIdx.x == 0) xout[(size_t)bb * VSTR + NN] = 0.5f / (E * (sum_in[bb] + xN));
    }
}

// out[i,j] = K*a_i*b_j*4096*cost (i,j<N), bins use E. FP8: K from K8; else in-place.
template <bool FP8>
__global__ __launch_bounds__(256) void final_kernel(float* __restrict__ out,
                                                    const unsigned char* __restrict__ K8,
                                                    const float* __restrict__ avec,
                                                    const float* __restrict__ bvec,
                                                    const float* __restrict__ pos,
                                                    const float* __restrict__ alpha) {
    int bb = blockIdx.y;
    int i0 = blockIdx.x * 16;
    __shared__ float as_[16], ys[16], xs2[16];
    int t = threadIdx.x;
    if (t < 16) {
        int i = i0 + t;
        as_[t] = (i < NP1) ? avec[(size_t)bb * VSTR + i] : 0.f;
        if (i < NN) {
            ys[t]  = pos[((size_t)bb * NN + i) * 2 + 0];
            xs2[t] = pos[((size_t)bb * NN + i) * 2 + 1];
        } else {
            ys[t] = 1e9f; xs2[t] = 1e9f;
        }
    }
    __syncthreads();
    float E = __expf(alpha[0]);
    float* outb = out + (size_t)bb * NP1 * NP1;
    const unsigned char* K8b = K8 + (size_t)bb * NN * NN;
    for (int j = t; j < NP1; j += 256) {
        float bj = bvec[(size_t)bb * VSTR + j];
        bool jin = (j < NN);
        float yj = 0.f, xj = 0.f;
        if (jin) {
            yj = pos[((size_t)bb * NN + j) * 2 + 0];
            xj = pos[((size_t)bb * NN + j) * 2 + 1];
        }
#pragma unroll 1
        for (int r = 0; r < 16; r++) {
            int i = i0 + r;
            if (i >= NP1) break;
            size_t idx = (size_t)i * NP1 + j;
            float v;
            if (i < NN && jin) {
                float Kv;
                if constexpr (FP8)
                    Kv = __builtin_amdgcn_cvt_f32_fp8((int)K8b[(size_t)i * NN + j], 0);
                else
                    Kv = outb[idx];
                bool c = (fabsf(ys[r] - yj) <= 0.1f) && (fabsf(xs2[r] - xj) <= 0.1f);
                v = c ? Kv * as_[r] * bj * 4096.0f : 0.0f;
            } else {
                v = E * as_[r] * bj * 4096.0f;
            }
            outb[idx] = v;
        }
    }
}

extern "C" void kernel_launch(void* const* d_in, const int* in_sizes, int n_in,
                              void* d_out, int out_size, void* d_ws, size_t ws_size,
                              hipStream_t stream) {
    const float* F     = (const float*)d_in[0];  // (B, D, N)
    const float* pos   = (const float*)d_in[1];  // (B, N, 2)
    const float* alpha = (const float*)d_in[3];  // (1,)
    float* out = (float*)d_out;
    float* ws  = (float*)d_ws;

    float* avec = ws;
    float* bvec = ws + BN * VSTR;
    float* sums = ws + 2 * BN * VSTR;                 // 41*BN floats (fallback path)
    int*   bar  = (int*)(sums + 41 * BN);             // BN x GRP arrival slots
    float* psum = (float*)(bar + BN * GRP);           // kept for layout stability
    unsigned char* K8  = (unsigned char*)(psum + 2 * BN * GRP);  // 33.5 MB fp8
    unsigned char* F16 = K8 + (size_t)BN * NN * NN;              // 8.4 MB bf16

    size_t need = (size_t)(2 * BN * VSTR + 41 * BN + 3 * BN * GRP) * 4
                + (size_t)BN * NN * NN + (size_t)BN * NN * DD * 2;
    bool fp8 = (ws_size >= need);

    hipLaunchKernelGGL(init_kernel, dim3(64), dim3(256), 0, stream, bvec, BN * VSTR,
                       sums, bar);

    if (fp8) {
        hipLaunchKernelGGL(f_to_bf16, dim3(NN / 64, DD / 64, BN), dim3(256), 0, stream,
                           F, F16);
        hipLaunchKernelGGL(build_k3, dim3(16, 16, BN), dim3(256), 0, stream, F16, K8);
        const unsigned char* Kp = K8;
        float* ap = avec; float* bp = bvec; int* brp = bar;
        const float* alp = alpha;
        void* params[5] = {(void*)&Kp, (void*)&ap, (void*)&bp, (void*)&brp,
                           (void*)&alp};
        hipLaunchCooperativeKernel((const void*)sink_persist, dim3(NBLK), dim3(1024),
                                   params, 0, stream);
        hipLaunchKernelGGL((final_kernel<true>), dim3((NP1 + 15) / 16, BN), dim3(256), 0,
                           stream, out, K8, avec, bvec, pos, alpha);
    } else {
        hipLaunchKernelGGL(build_k_f32, dim3(32, 32, BN), dim3(256), 0, stream, F, out);
        const float* xin = bvec;
        float* xout = avec;
        for (int p = 1; p <= 2 * NITER; p++) {
            hipLaunchKernelGGL(sink_pass_f32, dim3(NN / 16, BN), dim3(256), 0, stream,
                               out, xin, xout, sums + (p - 1) * BN, sums + p * BN, alpha);
            float* tmp = (float*)xin; xin = xout; xout = tmp;
        }
        hipLaunchKernelGGL((final_kernel<false>), dim3((NP1 + 15) / 16, BN), dim3(256), 0,
                           stream, out, K8, avec, bvec, pos, alpha);
    }
}

// Round 18
// 354.277 us; speedup vs baseline: 1.0373x; 1.0113x over previous
//
#include <hip/hip_runtime.h>
#include <math.h>

#define BN    8
#define NN    2048
#define NP1   2049
#define VSTR  2056   // padded a/b vector stride (floats), 16B-aligned rows
#define DD    256
#define NITER 20
#define NBLK  256    // persistent grid size, 1 block/CU
#define GRP   32     // blocks per batch (independent barrier group)

typedef float f32x2 __attribute__((ext_vector_type(2)));
typedef float f32x4_t __attribute__((ext_vector_type(4)));
typedef short short8 __attribute__((ext_vector_type(8)));

// ws layout: a[BN*VSTR] f32 | b[BN*VSTR] f32 | sums[41*BN] f32 | bar[BN*GRP] i32 |
//            psum[2*BN*GRP] f32 (unused) | K8[BN*NN*NN] fp8 | F16[BN*NN*DD] bf16

__global__ void init_kernel(float* __restrict__ bvec, int nb, float* __restrict__ sums,
                            int* __restrict__ bar) {
    int tid = blockIdx.x * blockDim.x + threadIdx.x;
    int stride = gridDim.x * blockDim.x;
    for (int i = tid; i < nb; i += stride) bvec[i] = 1.0f;            // v0 = 0 -> b = 1
    for (int i = tid; i < 41 * BN; i += stride) sums[i] = (i < BN) ? (float)NN : 0.0f;
    if (tid < BN * GRP) bar[tid] = 0;
}

__device__ __forceinline__ unsigned short f2bf(float f) {
    unsigned u = __builtin_bit_cast(unsigned, f);
    return (unsigned short)((u + 0x7fffu + ((u >> 16) & 1u)) >> 16);   // RNE
}

// Pre-pass: F (B,D,N) f32 -> F16 (B,N,D) bf16, LDS-tiled 64x64 transpose.
__global__ __launch_bounds__(256) void f_to_bf16(const float* __restrict__ F,
                                                 unsigned char* __restrict__ F16) {
    int x0 = blockIdx.x * 64, k0 = blockIdx.y * 64, bb = blockIdx.z;
    __shared__ unsigned short tile[64][68];    // 68-pad: 8B-aligned rows
    int t = threadIdx.x;
    const float* Fb = F + (size_t)bb * DD * NN;
#pragma unroll
    for (int q = 0; q < 16; q++) {
        int idx = q * 256 + t;
        int kk = idx >> 6, xx = idx & 63;
        tile[xx][kk] = f2bf(Fb[(size_t)(k0 + kk) * NN + x0 + xx]);
    }
    __syncthreads();
    int r = t >> 2, c = t & 3;                 // row, 16-elem chunk
    const unsigned long long* src = (const unsigned long long*)&tile[r][c * 16];
    unsigned long long v0 = src[0], v1 = src[1], v2 = src[2], v3 = src[3];
    unsigned char* dst = F16 + (((size_t)bb * NN + x0 + r) * DD + k0) * 2 + c * 32;
    ((unsigned long long*)dst)[0] = v0;
    ((unsigned long long*)dst)[1] = v1;
    ((unsigned long long*)dst)[2] = v2;
    ((unsigned long long*)dst)[3] = v3;
}

// build_k v4: symmetric-pair MFMA build. Only the 136 upper-triangle tile
// pairs (ti<=tj) are computed; each block emits BOTH K[i-tile][j-tile]
// (row-major via strided Cm reads, as R15-R17) AND K[j-tile][i-tile]
// (Cm rows ARE the transposed tile -> contiguous uint4 stores). Halves
// MFMA work + F16 reads; store bytes unchanged. Cm aliases Ab/Bb (R17).
__global__ __launch_bounds__(256) void build_k3(const unsigned char* __restrict__ F16,
                                                unsigned char* __restrict__ K8) {
    // decode linear upper-triangle index -> (ti, tj), 16x16 tile grid
    int idx = blockIdx.x, ti = 0;
    while (idx >= 16 - ti) { idx -= 16 - ti; ti++; }
    int tj = ti + idx;
    int bb = blockIdx.z;
    int i0 = ti * 128, j0 = tj * 128;
    const unsigned char* F16b = F16 + (size_t)bb * NN * DD * 2;

    __shared__ __align__(16) unsigned char Smem[128 * 80 * 2];   // 20480 B
    unsigned char* Ab = Smem;                    // [x][k] bf16, 80B rows
    unsigned char* Bb = Smem + 128 * 80;
    unsigned char* Cm = Smem;                    // ALIAS: col-major fp8 [c][i]

    int t = threadIdx.x;
    int w = t >> 6, l = t & 63;
    int wr = w >> 1, wc = w & 1;           // wave grid 2x2 -> 64x64 per wave
    int g = l >> 4, c16 = l & 15;

    f32x4_t acc[4][4];
#pragma unroll
    for (int r = 0; r < 4; r++)
#pragma unroll
        for (int c = 0; c < 4; c++) acc[r][c] = (f32x4_t){0.f, 0.f, 0.f, 0.f};

    int xr = t >> 2, q4 = t & 3;
    // prefetch k-step 0 into registers
    uint4 va0 = *(const uint4*)(F16b + ((size_t)(i0 + xr) * DD) * 2 + q4 * 16);
    uint4 va1 = *(const uint4*)(F16b + ((size_t)(i0 + 64 + xr) * DD) * 2 + q4 * 16);
    uint4 vb0 = *(const uint4*)(F16b + ((size_t)(j0 + xr) * DD) * 2 + q4 * 16);
    uint4 vb1 = *(const uint4*)(F16b + ((size_t)(j0 + 64 + xr) * DD) * 2 + q4 * 16);

    for (int k0 = 0; k0 < DD; k0 += 32) {
        *(uint4*)(Ab + xr * 80 + q4 * 16)        = va0;
        *(uint4*)(Ab + (64 + xr) * 80 + q4 * 16) = va1;
        *(uint4*)(Bb + xr * 80 + q4 * 16)        = vb0;
        *(uint4*)(Bb + (64 + xr) * 80 + q4 * 16) = vb1;
        __syncthreads();

        if (k0 + 32 < DD) {
            int kn = (k0 + 32) * 2;
            va0 = *(const uint4*)(F16b + (size_t)(i0 + xr) * DD * 2 + kn + q4 * 16);
            va1 = *(const uint4*)(F16b + (size_t)(i0 + 64 + xr) * DD * 2 + kn + q4 * 16);
            vb0 = *(const uint4*)(F16b + (size_t)(j0 + xr) * DD * 2 + kn + q4 * 16);
            vb1 = *(const uint4*)(F16b + (size_t)(j0 + 64 + xr) * DD * 2 + kn + q4 * 16);
        }

        short8 af[4], bf_[4];
#pragma unroll
        for (int rf = 0; rf < 4; rf++)
            af[rf] = *(const short8*)(Ab + (wr * 64 + rf * 16 + c16) * 80 + g * 16);
#pragma unroll
        for (int cf = 0; cf < 4; cf++)
            bf_[cf] = *(const short8*)(Bb + (wc * 64 + cf * 16 + c16) * 80 + g * 16);
#pragma unroll
        for (int rf = 0; rf < 4; rf++)
#pragma unroll
            for (int cf = 0; cf < 4; cf++)
                acc[rf][cf] = __builtin_amdgcn_mfma_f32_16x16x32_bf16(
                    af[rf], bf_[cf], acc[rf][cf], 0, 0, 0);
        __syncthreads();
    }

    // epilogue: exp, diag-zero, pack -> col-major fp8 LDS (Cm aliases Ab/Bb)
#pragma unroll
    for (int rf = 0; rf < 4; rf++) {
#pragma unroll
        for (int cf = 0; cf < 4; cf++) {
            int ib = wr * 64 + rf * 16 + g * 4;
            int jl = wc * 64 + cf * 16 + c16;
            float v[4];
#pragma unroll
            for (int r = 0; r < 4; r++) {
                float e = __expf(acc[rf][cf][r] * 0.0625f);   // 1/sqrt(256)
                if (i0 + ib + r == j0 + jl) e = 0.0f;
                v[r] = e;
            }
            unsigned wd = __builtin_amdgcn_cvt_pk_fp8_f32(v[0], v[1], 0, false);
            wd = __builtin_amdgcn_cvt_pk_fp8_f32(v[2], v[3], wd, true);
            *(unsigned*)(Cm + jl * 132 + ib) = wd;
        }
    }
    __syncthreads();

    unsigned char* K8b = K8 + (size_t)bb * NN * NN;
    int il = t >> 1, hh = t & 1;

    // (1) row-major store of tile (i0, j0): strided Cm column gather (as R17)
    {
        unsigned wrow[16];
#pragma unroll
        for (int cq = 0; cq < 16; cq++) {
            int cb = hh * 64 + cq * 4;
            unsigned b0 = Cm[(cb + 0) * 132 + il];
            unsigned b1 = Cm[(cb + 1) * 132 + il];
            unsigned b2 = Cm[(cb + 2) * 132 + il];
            unsigned b3 = Cm[(cb + 3) * 132 + il];
            wrow[cq] = b0 | (b1 << 8) | (b2 << 16) | (b3 << 24);
        }
        uint4* dst = (uint4*)(K8b + (size_t)(i0 + il) * NN + j0 + hh * 64);
#pragma unroll
        for (int qq = 0; qq < 4; qq++) {
            uint4 u; u.x = wrow[qq * 4]; u.y = wrow[qq * 4 + 1];
            u.z = wrow[qq * 4 + 2]; u.w = wrow[qq * 4 + 3];
            dst[qq] = u;
        }
    }
    // (2) mirror store of tile (j0, i0): Cm rows are contiguous = transposed tile
    if (tj > ti) {
        const uint4* srcp = (const uint4*)(Cm + il * 132 + hh * 64);
        uint4 u0 = srcp[0], u1 = srcp[1], u2 = srcp[2], u3 = srcp[3];
        uint4* dst = (uint4*)(K8b + (size_t)(j0 + il) * NN + i0 + hh * 64);
        dst[0] = u0; dst[1] = u1; dst[2] = u2; dst[3] = u3;
    }
}

// fp32 fallback build (writes into out, stride NP1). Symmetric-half as before.
__global__ __launch_bounds__(256) void build_k_f32(const float* __restrict__ F,
                                                   float* __restrict__ out) {
    int ti = blockIdx.x, tj = blockIdx.y, bb = blockIdx.z;
    if (tj < ti) return;
    __shared__ float As[32][64];
    __shared__ float Bs[32][64];
    int t  = threadIdx.x;
    int tx = t & 15, ty = t >> 4;
    float acc[4][4] = {};
    const float* Fb = F + (size_t)bb * DD * NN;
    int i0 = ti * 64, j0 = tj * 64;
    for (int k0 = 0; k0 < DD; k0 += 32) {
#pragma unroll
        for (int v = 0; v < 2; v++) {
            int f = t + 256 * v;
            int row = f >> 4, c4 = (f & 15) * 4;
            *(float4*)&As[row][c4] = *(const float4*)&Fb[(size_t)(k0 + row) * NN + i0 + c4];
            *(float4*)&Bs[row][c4] = *(const float4*)&Fb[(size_t)(k0 + row) * NN + j0 + c4];
        }
        __syncthreads();
#pragma unroll
        for (int k = 0; k < 32; k++) {
            float4 av = *(float4*)&As[k][ty * 4];
            float4 bv = *(float4*)&Bs[k][tx * 4];
            float ar[4] = {av.x, av.y, av.z, av.w};
            float br[4] = {bv.x, bv.y, bv.z, bv.w};
#pragma unroll
            for (int r = 0; r < 4; r++)
#pragma unroll
                for (int c = 0; c < 4; c++)
                    acc[r][c] = fmaf(ar[r], br[c], acc[r][c]);
        }
        __syncthreads();
    }
#pragma unroll
    for (int r = 0; r < 4; r++) {
        int i = i0 + ty * 4 + r;
#pragma unroll
        for (int c = 0; c < 4; c++) {
            int j = j0 + tx * 4 + c;
            float Kv = (i == j) ? 0.0f : __expf(acc[r][c] * 0.0625f);
            float* outb = out + (size_t)bb * NP1 * NP1;
            outb[(size_t)i * NP1 + j] = Kv;
            if (tj > ti) outb[(size_t)j * NP1 + i] = Kv;
        }
    }
}

// Persistent Sinkhorn, 128 KB fp8 K-shard in LDS. Fence-free sc1 exchange
// (R15, verified): x values are agent-scope relaxed atomics ordered by
// __syncthreads()'s vmcnt(0) drain; S(x) computed locally. Byte-identical R15.
__global__ __launch_bounds__(1024) void sink_persist(const unsigned char* __restrict__ K8,
                                                     float* __restrict__ avec,
                                                     float* __restrict__ bvec,
                                                     int* __restrict__ bar,
                                                     const float* __restrict__ alpha) {
    int blk   = blockIdx.x;
    int batch = blk & 7;           // XCD id under round-robin dispatch
    int rb    = blk >> 3;
    int tid   = threadIdx.x;
    int seg   = tid & 15;
    int row   = tid >> 4;          // row within the 64-row shard
    int grow  = rb * 64 + row;     // global row

    __shared__ __align__(16) unsigned char Ks[64 * 2048];   // 128 KB fp8 shard
    __shared__ float xs[16 * 132];                          // padded x stage
    __shared__ float wsum[16];

    {
        const int4* gsrc = (const int4*)(K8 + ((size_t)batch * NN + (size_t)rb * 64) * NN);
#pragma unroll
        for (int q = 0; q < 8; q++) {
            int idx = q * 1024 + tid;
            int4 v = gsrc[idx];
            int g = idx * 16;
            int r_ = g >> 11, bir = g & 2047;
            *(int4*)&Ks[r_ * 2048 + (bir ^ (((bir >> 7) & 7) << 4))] = v;
        }
    }   // first pass's __syncthreads() covers this staging

    float* av = avec + (size_t)batch * VSTR;
    float* bv = bvec + (size_t)batch * VSTR;
    int*   gbar = bar + batch * GRP;
    float E    = __expf(alpha[0]);
    float binA = 0.f, binB = 1.0f;
    int   ep   = 0;
    const float4* xp4 = (const float4*)(xs + seg * 132);
    const int kbase = row * 2048;
    const int sb    = seg * 128;
    const int sx    = (seg & 7) << 4;

#define MAC16(KI, ACC)                                                          \
    {                                                                           \
        int4 kv = *(const int4*)&Ks[kbase + ((sb + (KI) * 16) ^ sx)];           \
        float4 xa = xp4[(KI) * 4 + 0], xb = xp4[(KI) * 4 + 1];                  \
        float4 xc = xp4[(KI) * 4 + 2], xd = xp4[(KI) * 4 + 3];                  \
        f32x2 p0 = __builtin_amdgcn_cvt_pk_f32_fp8(kv.x, false);                \
        f32x2 p1 = __builtin_amdgcn_cvt_pk_f32_fp8(kv.x, true);                 \
        f32x2 p2 = __builtin_amdgcn_cvt_pk_f32_fp8(kv.y, false);                \
        f32x2 p3 = __builtin_amdgcn_cvt_pk_f32_fp8(kv.y, true);                 \
        f32x2 p4 = __builtin_amdgcn_cvt_pk_f32_fp8(kv.z, false);                \
        f32x2 p5 = __builtin_amdgcn_cvt_pk_f32_fp8(kv.z, true);                 \
        f32x2 p6 = __builtin_amdgcn_cvt_pk_f32_fp8(kv.w, false);                \
        f32x2 p7 = __builtin_amdgcn_cvt_pk_f32_fp8(kv.w, true);                 \
        ACC = fmaf(p0.x, xa.x, ACC); ACC = fmaf(p0.y, xa.y, ACC);               \
        ACC = fmaf(p1.x, xa.z, ACC); ACC = fmaf(p1.y, xa.w, ACC);               \
        ACC = fmaf(p2.x, xb.x, ACC); ACC = fmaf(p2.y, xb.y, ACC);               \
        ACC = fmaf(p3.x, xb.z, ACC); ACC = fmaf(p3.y, xb.w, ACC);               \
        ACC = fmaf(p4.x, xc.x, ACC); ACC = fmaf(p4.y, xc.y, ACC);               \
        ACC = fmaf(p5.x, xc.z, ACC); ACC = fmaf(p5.y, xc.w, ACC);               \
        ACC = fmaf(p6.x, xd.x, ACC); ACC = fmaf(p6.y, xd.y, ACC);               \
        ACC = fmaf(p7.x, xd.z, ACC); ACC = fmaf(p7.y, xd.w, ACC);               \
    }

#define SINK_PASS(XIN, XOUT, BIN_IN, BIN_OUT, LAST)                             \
    {                                                                           \
        float sv;                                                               \
        {   /* stage XIN via sc1 atomic loads (coherence-point reads) */        \
            float v0 = __hip_atomic_load((XIN) + 2 * tid, __ATOMIC_RELAXED,     \
                                         __HIP_MEMORY_SCOPE_AGENT);             \
            float v1 = __hip_atomic_load((XIN) + 2 * tid + 1, __ATOMIC_RELAXED, \
                                         __HIP_MEMORY_SCOPE_AGENT);             \
            int j = tid * 2;                                                    \
            float* d = xs + ((j >> 7) * 132 + (j & 127));                       \
            d[0] = v0; d[1] = v1;                                               \
            sv = v0 + v1;                                                       \
        }                                                                       \
        sv += __shfl_xor(sv, 1);  sv += __shfl_xor(sv, 2);                      \
        sv += __shfl_xor(sv, 4);  sv += __shfl_xor(sv, 8);                      \
        sv += __shfl_xor(sv, 16); sv += __shfl_xor(sv, 32);                     \
        if ((tid & 63) == 0) wsum[tid >> 6] = sv;                               \
        __syncthreads();                                                        \
        float S_cur = 0.f;                                                      \
        _Pragma("unroll")                                                       \
        for (int w2 = 0; w2 < 16; w2++) S_cur += wsum[w2];                      \
        float dot0 = 0.f, dot1 = 0.f;                                           \
        MAC16(0, dot0) MAC16(1, dot1) MAC16(2, dot0) MAC16(3, dot1)             \
        MAC16(4, dot0) MAC16(5, dot1) MAC16(6, dot0) MAC16(7, dot1)             \
        float dot = dot0 + dot1;                                                \
        dot += __shfl_xor(dot, 1);                                              \
        dot += __shfl_xor(dot, 2);                                              \
        dot += __shfl_xor(dot, 4);                                              \
        dot += __shfl_xor(dot, 8);                                              \
        float val = (1.0f / 4096.0f) / (dot + E * (BIN_IN));                    \
        BIN_OUT = 0.5f / (E * (S_cur + (BIN_IN)));                              \
        if ((tid & 15) == 0)                                                    \
            __hip_atomic_store(&(XOUT)[grow], val, __ATOMIC_RELAXED,            \
                               __HIP_MEMORY_SCOPE_AGENT);                       \
        __syncthreads();   /* vmcnt(0) drain: val stores complete (sc1) */      \
        if (!(LAST)) {                                                          \
            ep++;                                                               \
            if (tid == 0)                                                       \
                __hip_atomic_store(&gbar[rb], ep, __ATOMIC_RELAXED,             \
                                   __HIP_MEMORY_SCOPE_AGENT);                   \
            if (tid < GRP) {                                                    \
                while (__hip_atomic_load(&gbar[tid], __ATOMIC_RELAXED,          \
                                         __HIP_MEMORY_SCOPE_AGENT) < ep)        \
                    __builtin_amdgcn_s_sleep(1);                                \
            }                                                                   \
            __syncthreads();                                                    \
        }                                                                       \
    }

    for (int it2 = 0; it2 < NITER; it2++) {
        SINK_PASS(bv, av, binB, binA, false);
        SINK_PASS(av, bv, binA, binB, (it2 == NITER - 1));
    }
#undef SINK_PASS
#undef MAC16

    if (tid == 0) { av[NN] = binA; bv[NN] = binB; }
}

// fp32 fallback pass (K in d_out, stride NP1) for ws-too-small case.
__global__ __launch_bounds__(256) void sink_pass_f32(const float* __restrict__ K,
                                                     const float* __restrict__ xin,
                                                     float* __restrict__ xout,
                                                     const float* __restrict__ sum_in,
                                                     float* __restrict__ sum_out,
                                                     const float* __restrict__ alpha) {
    int bb = blockIdx.y;
    int i0 = blockIdx.x * 16;
    __shared__ float xsl[NN];
    __shared__ float rowa[16];
    const float* xinb = xin + (size_t)bb * VSTR;
    int t = threadIdx.x;
    for (int j = t; j < NN; j += 256) xsl[j] = xinb[j];
    __syncthreads();
    float E  = __expf(alpha[0]);
    float xN = xinb[NN];
    int wave = t >> 6, lane = t & 63;
    const float* Kb = K + (size_t)bb * NP1 * NP1;
    for (int r = wave; r < 16; r += 4) {
        int i = i0 + r;
        const float* rowp = Kb + (size_t)i * NP1;
        float acc = 0.f;
        for (int j = lane; j < NN; j += 64) acc = fmaf(rowp[j], xsl[j], acc);
#pragma unroll
        for (int off = 32; off >= 1; off >>= 1) acc += __shfl_xor(acc, off);
        if (lane == 0) {
            float v = (1.0f / 4096.0f) / (acc + E * xN);
            xout[(size_t)bb * VSTR + i] = v;
            rowa[r] = v;
        }
    }
    __syncthreads();
    if (t == 0) {
        float s = 0.f;
#pragma unroll
        for (int r = 0; r < 16; r++) s += rowa[r];
        atomicAdd(sum_out + bb, s);
        if (blockIdx.x == 0) xout[(size_t)bb * VSTR + NN] = 0.5f / (E * (sum_in[bb] + xN));
    }
}

// out[i,j] = K*a_i*b_j*4096*cost (i,j<N), bins use E. FP8: K from K8; else in-place.
template <bool FP8>
__global__ __launch_bounds__(256) void final_kernel(float* __restrict__ out,
                                                    const unsigned char* __restrict__ K8,
                                                    const float* __restrict__ avec,
                                                    const float* __restrict__ bvec,
                                                    const float* __restrict__ pos,
                                                    const float* __restrict__ alpha) {
    int bb = blockIdx.y;
    int i0 = blockIdx.x * 16;
    __shared__ float as_[16], ys[16], xs2[16];
    int t = threadIdx.x;
    if (t < 16) {
        int i = i0 + t;
        as_[t] = (i < NP1) ? avec[(size_t)bb * VSTR + i] : 0.f;
        if (i < NN) {
            ys[t]  = pos[((size_t)bb * NN + i) * 2 + 0];
            xs2[t] = pos[((size_t)bb * NN + i) * 2 + 1];
        } else {
            ys[t] = 1e9f; xs2[t] = 1e9f;
        }
    }
    __syncthreads();
    float E = __expf(alpha[0]);
    float* outb = out + (size_t)bb * NP1 * NP1;
    const unsigned char* K8b = K8 + (size_t)bb * NN * NN;
    for (int j = t; j < NP1; j += 256) {
        float bj = bvec[(size_t)bb * VSTR + j];
        bool jin = (j < NN);
        float yj = 0.f, xj = 0.f;
        if (jin) {
            yj = pos[((size_t)bb * NN + j) * 2 + 0];
            xj = pos[((size_t)bb * NN + j) * 2 + 1];
        }
#pragma unroll 1
        for (int r = 0; r < 16; r++) {
            int i = i0 + r;
            if (i >= NP1) break;
            size_t idx = (size_t)i * NP1 + j;
            float v;
            if (i < NN && jin) {
                float Kv;
                if constexpr (FP8)
                    Kv = __builtin_amdgcn_cvt_f32_fp8((int)K8b[(size_t)i * NN + j], 0);
                else
                    Kv = outb[idx];
                bool c = (fabsf(ys[r] - yj) <= 0.1f) && (fabsf(xs2[r] - xj) <= 0.1f);
                v = c ? Kv * as_[r] * bj * 4096.0f : 0.0f;
            } else {
                v = E * as_[r] * bj * 4096.0f;
            }
            outb[idx] = v;
        }
    }
}

extern "C" void kernel_launch(void* const* d_in, const int* in_sizes, int n_in,
                              void* d_out, int out_size, void* d_ws, size_t ws_size,
                              hipStream_t stream) {
    const float* F     = (const float*)d_in[0];  // (B, D, N)
    const float* pos   = (const float*)d_in[1];  // (B, N, 2)
    const float* alpha = (const float*)d_in[3];  // (1,)
    float* out = (float*)d_out;
    float* ws  = (float*)d_ws;

    float* avec = ws;
    float* bvec = ws + BN * VSTR;
    float* sums = ws + 2 * BN * VSTR;                 // 41*BN floats (fallback path)
    int*   bar  = (int*)(sums + 41 * BN);             // BN x GRP arrival slots
    float* psum = (float*)(bar + BN * GRP);           // kept for layout stability
    unsigned char* K8  = (unsigned char*)(psum + 2 * BN * GRP);  // 33.5 MB fp8
    unsigned char* F16 = K8 + (size_t)BN * NN * NN;              // 8.4 MB bf16

    size_t need = (size_t)(2 * BN * VSTR + 41 * BN + 3 * BN * GRP) * 4
                + (size_t)BN * NN * NN + (size_t)BN * NN * DD * 2;
    bool fp8 = (ws_size >= need);

    hipLaunchKernelGGL(init_kernel, dim3(64), dim3(256), 0, stream, bvec, BN * VSTR,
                       sums, bar);

    if (fp8) {
        hipLaunchKernelGGL(f_to_bf16, dim3(NN / 64, DD / 64, BN), dim3(256), 0, stream,
                           F, F16);
        hipLaunchKernelGGL(build_k3, dim3(136, 1, BN), dim3(256), 0, stream, F16, K8);
        const unsigned char* Kp = K8;
        float* ap = avec; float* bp = bvec; int* brp = bar;
        const float* alp = alpha;
        void* params[5] = {(void*)&Kp, (void*)&ap, (void*)&bp, (void*)&brp,
                           (void*)&alp};
        hipLaunchCooperativeKernel((const void*)sink_persist, dim3(NBLK), dim3(1024),
                                   params, 0, stream);
        hipLaunchKernelGGL((final_kernel<true>), dim3((NP1 + 15) / 16, BN), dim3(256), 0,
                           stream, out, K8, avec, bvec, pos, alpha);
    } else {
        hipLaunchKernelGGL(build_k_f32, dim3(32, 32, BN), dim3(256), 0, stream, F, out);
        const float* xin = bvec;
        float* xout = avec;
        for (int p = 1; p <= 2 * NITER; p++) {
            hipLaunchKernelGGL(sink_pass_f32, dim3(NN / 16, BN), dim3(256), 0, stream,
                               out, xin, xout, sums + (p - 1) * BN, sums + p * BN, alpha);
            float* tmp = (float*)xin; xin = xout; xout = tmp;
        }
        hipLaunchKernelGGL((final_kernel<false>), dim3((NP1 + 15) / 16, BN), dim3(256), 0,
                           stream, out, K8, avec, bvec, pos, alpha);
    }
}

// Round 19
// 324.307 us; speedup vs baseline: 1.1332x; 1.0924x over previous
//
#include <hip/hip_runtime.h>
#include <math.h>

#define BN    8
#define NN    2048
#define NP1   2049
#define VSTR  2056   // padded a/b vector stride (floats), 16B-aligned rows
#define DD    256
#define NITER 20
#define NBLK  256    // persistent grid size, 1 block/CU (LDS-capacity-pinned)
#define GRP   32     // blocks per batch (independent barrier group)

typedef float f32x2 __attribute__((ext_vector_type(2)));
typedef float f32x4_t __attribute__((ext_vector_type(4)));
typedef short short8 __attribute__((ext_vector_type(8)));

// ws layout: a[BN*VSTR] f32 | b[BN*VSTR] f32 | sums[41*BN] f32 | bar[BN*GRP] i32 |
//            psum[2*BN*GRP] f32 (unused) | K8[BN*NN*NN] fp8 | F16[BN*NN*DD] bf16

__global__ void init_kernel(float* __restrict__ bvec, int nb, float* __restrict__ sums,
                            int* __restrict__ bar) {
    int tid = blockIdx.x * blockDim.x + threadIdx.x;
    int stride = gridDim.x * blockDim.x;
    for (int i = tid; i < nb; i += stride) bvec[i] = 1.0f;            // v0 = 0 -> b = 1
    for (int i = tid; i < 41 * BN; i += stride) sums[i] = (i < BN) ? (float)NN : 0.0f;
    if (tid < BN * GRP) bar[tid] = 0;
}

__device__ __forceinline__ unsigned short f2bf(float f) {
    unsigned u = __builtin_bit_cast(unsigned, f);
    return (unsigned short)((u + 0x7fffu + ((u >> 16) & 1u)) >> 16);   // RNE
}

// Pre-pass: F (B,D,N) f32 -> F16 (B,N,D) bf16, LDS-tiled 64x64 transpose.
__global__ __launch_bounds__(256) void f_to_bf16(const float* __restrict__ F,
                                                 unsigned char* __restrict__ F16) {
    int x0 = blockIdx.x * 64, k0 = blockIdx.y * 64, bb = blockIdx.z;
    __shared__ unsigned short tile[64][68];    // 68-pad: 8B-aligned rows
    int t = threadIdx.x;
    const float* Fb = F + (size_t)bb * DD * NN;
#pragma unroll
    for (int q = 0; q < 16; q++) {
        int idx = q * 256 + t;
        int kk = idx >> 6, xx = idx & 63;
        tile[xx][kk] = f2bf(Fb[(size_t)(k0 + kk) * NN + x0 + xx]);
    }
    __syncthreads();
    int r = t >> 2, c = t & 3;                 // row, 16-elem chunk
    const unsigned long long* src = (const unsigned long long*)&tile[r][c * 16];
    unsigned long long v0 = src[0], v1 = src[1], v2 = src[2], v3 = src[3];
    unsigned char* dst = F16 + (((size_t)bb * NN + x0 + r) * DD + k0) * 2 + c * 32;
    ((unsigned long long*)dst)[0] = v0;
    ((unsigned long long*)dst)[1] = v1;
    ((unsigned long long*)dst)[2] = v2;
    ((unsigned long long*)dst)[3] = v3;
}

// build_k v4: symmetric-pair MFMA build (R18, verified). 136 upper-triangle
// tile pairs; each block emits tile (i,j) row-major + mirror (j,i) via the
// col-major Cm bounce. Cm aliases Ab/Bb.
__global__ __launch_bounds__(256) void build_k3(const unsigned char* __restrict__ F16,
                                                unsigned char* __restrict__ K8) {
    int idx = blockIdx.x, ti = 0;
    while (idx >= 16 - ti) { idx -= 16 - ti; ti++; }
    int tj = ti + idx;
    int bb = blockIdx.z;
    int i0 = ti * 128, j0 = tj * 128;
    const unsigned char* F16b = F16 + (size_t)bb * NN * DD * 2;

    __shared__ __align__(16) unsigned char Smem[128 * 80 * 2];   // 20480 B
    unsigned char* Ab = Smem;                    // [x][k] bf16, 80B rows
    unsigned char* Bb = Smem + 128 * 80;
    unsigned char* Cm = Smem;                    // ALIAS: col-major fp8 [c][i]

    int t = threadIdx.x;
    int w = t >> 6, l = t & 63;
    int wr = w >> 1, wc = w & 1;           // wave grid 2x2 -> 64x64 per wave
    int g = l >> 4, c16 = l & 15;

    f32x4_t acc[4][4];
#pragma unroll
    for (int r = 0; r < 4; r++)
#pragma unroll
        for (int c = 0; c < 4; c++) acc[r][c] = (f32x4_t){0.f, 0.f, 0.f, 0.f};

    int xr = t >> 2, q4 = t & 3;
    uint4 va0 = *(const uint4*)(F16b + ((size_t)(i0 + xr) * DD) * 2 + q4 * 16);
    uint4 va1 = *(const uint4*)(F16b + ((size_t)(i0 + 64 + xr) * DD) * 2 + q4 * 16);
    uint4 vb0 = *(const uint4*)(F16b + ((size_t)(j0 + xr) * DD) * 2 + q4 * 16);
    uint4 vb1 = *(const uint4*)(F16b + ((size_t)(j0 + 64 + xr) * DD) * 2 + q4 * 16);

    for (int k0 = 0; k0 < DD; k0 += 32) {
        *(uint4*)(Ab + xr * 80 + q4 * 16)        = va0;
        *(uint4*)(Ab + (64 + xr) * 80 + q4 * 16) = va1;
        *(uint4*)(Bb + xr * 80 + q4 * 16)        = vb0;
        *(uint4*)(Bb + (64 + xr) * 80 + q4 * 16) = vb1;
        __syncthreads();

        if (k0 + 32 < DD) {
            int kn = (k0 + 32) * 2;
            va0 = *(const uint4*)(F16b + (size_t)(i0 + xr) * DD * 2 + kn + q4 * 16);
            va1 = *(const uint4*)(F16b + (size_t)(i0 + 64 + xr) * DD * 2 + kn + q4 * 16);
            vb0 = *(const uint4*)(F16b + (size_t)(j0 + xr) * DD * 2 + kn + q4 * 16);
            vb1 = *(const uint4*)(F16b + (size_t)(j0 + 64 + xr) * DD * 2 + kn + q4 * 16);
        }

        short8 af[4], bf_[4];
#pragma unroll
        for (int rf = 0; rf < 4; rf++)
            af[rf] = *(const short8*)(Ab + (wr * 64 + rf * 16 + c16) * 80 + g * 16);
#pragma unroll
        for (int cf = 0; cf < 4; cf++)
            bf_[cf] = *(const short8*)(Bb + (wc * 64 + cf * 16 + c16) * 80 + g * 16);
#pragma unroll
        for (int rf = 0; rf < 4; rf++)
#pragma unroll
            for (int cf = 0; cf < 4; cf++)
                acc[rf][cf] = __builtin_amdgcn_mfma_f32_16x16x32_bf16(
                    af[rf], bf_[cf], acc[rf][cf], 0, 0, 0);
        __syncthreads();
    }

#pragma unroll
    for (int rf = 0; rf < 4; rf++) {
#pragma unroll
        for (int cf = 0; cf < 4; cf++) {
            int ib = wr * 64 + rf * 16 + g * 4;
            int jl = wc * 64 + cf * 16 + c16;
            float v[4];
#pragma unroll
            for (int r = 0; r < 4; r++) {
                float e = __expf(acc[rf][cf][r] * 0.0625f);   // 1/sqrt(256)
                if (i0 + ib + r == j0 + jl) e = 0.0f;
                v[r] = e;
            }
            unsigned wd = __builtin_amdgcn_cvt_pk_fp8_f32(v[0], v[1], 0, false);
            wd = __builtin_amdgcn_cvt_pk_fp8_f32(v[2], v[3], wd, true);
            *(unsigned*)(Cm + jl * 132 + ib) = wd;
        }
    }
    __syncthreads();

    unsigned char* K8b = K8 + (size_t)bb * NN * NN;
    int il = t >> 1, hh = t & 1;
    {
        unsigned wrow[16];
#pragma unroll
        for (int cq = 0; cq < 16; cq++) {
            int cb = hh * 64 + cq * 4;
            unsigned b0 = Cm[(cb + 0) * 132 + il];
            unsigned b1 = Cm[(cb + 1) * 132 + il];
            unsigned b2 = Cm[(cb + 2) * 132 + il];
            unsigned b3 = Cm[(cb + 3) * 132 + il];
            wrow[cq] = b0 | (b1 << 8) | (b2 << 16) | (b3 << 24);
        }
        uint4* dst = (uint4*)(K8b + (size_t)(i0 + il) * NN + j0 + hh * 64);
#pragma unroll
        for (int qq = 0; qq < 4; qq++) {
            uint4 u; u.x = wrow[qq * 4]; u.y = wrow[qq * 4 + 1];
            u.z = wrow[qq * 4 + 2]; u.w = wrow[qq * 4 + 3];
            dst[qq] = u;
        }
    }
    if (tj > ti) {
        const uint4* srcp = (const uint4*)(Cm + il * 132 + hh * 64);
        uint4 u0 = srcp[0], u1 = srcp[1], u2 = srcp[2], u3 = srcp[3];
        uint4* dst = (uint4*)(K8b + (size_t)(j0 + il) * NN + i0 + hh * 64);
        dst[0] = u0; dst[1] = u1; dst[2] = u2; dst[3] = u3;
    }
}

// fp32 fallback build (writes into out, stride NP1). Symmetric-half as before.
__global__ __launch_bounds__(256) void build_k_f32(const float* __restrict__ F,
                                                   float* __restrict__ out) {
    int ti = blockIdx.x, tj = blockIdx.y, bb = blockIdx.z;
    if (tj < ti) return;
    __shared__ float As[32][64];
    __shared__ float Bs[32][64];
    int t  = threadIdx.x;
    int tx = t & 15, ty = t >> 4;
    float acc[4][4] = {};
    const float* Fb = F + (size_t)bb * DD * NN;
    int i0 = ti * 64, j0 = tj * 64;
    for (int k0 = 0; k0 < DD; k0 += 32) {
#pragma unroll
        for (int v = 0; v < 2; v++) {
            int f = t + 256 * v;
            int row = f >> 4, c4 = (f & 15) * 4;
            *(float4*)&As[row][c4] = *(const float4*)&Fb[(size_t)(k0 + row) * NN + i0 + c4];
            *(float4*)&Bs[row][c4] = *(const float4*)&Fb[(size_t)(k0 + row) * NN + j0 + c4];
        }
        __syncthreads();
#pragma unroll
        for (int k = 0; k < 32; k++) {
            float4 av = *(float4*)&As[k][ty * 4];
            float4 bv = *(float4*)&Bs[k][tx * 4];
            float ar[4] = {av.x, av.y, av.z, av.w};
            float br[4] = {bv.x, bv.y, bv.z, bv.w};
#pragma unroll
            for (int r = 0; r < 4; r++)
#pragma unroll
                for (int c = 0; c < 4; c++)
                    acc[r][c] = fmaf(ar[r], br[c], acc[r][c]);
        }
        __syncthreads();
    }
#pragma unroll
    for (int r = 0; r < 4; r++) {
        int i = i0 + ty * 4 + r;
#pragma unroll
        for (int c = 0; c < 4; c++) {
            int j = j0 + tx * 4 + c;
            float Kv = (i == j) ? 0.0f : __expf(acc[r][c] * 0.0625f);
            float* outb = out + (size_t)bb * NP1 * NP1;
            outb[(size_t)i * NP1 + j] = Kv;
            if (tj > ti) outb[(size_t)j * NP1 + i] = Kv;
        }
    }
}

// Persistent Sinkhorn, 128 KB fp8 K-shard in LDS. Fence-free sc1 exchange
// (R15, verified). R18->R19: launched as a PLAIN kernel, not cooperative —
// we never call cg grid_sync (own flag barriers only), and co-residency is
// guaranteed by LDS capacity: 136.5 KB/block > 160/2 KB -> exactly 1 block/CU,
// 256 blocks on 256 CUs, none can retire before all are resident.
__global__ __launch_bounds__(1024) void sink_persist(const unsigned char* __restrict__ K8,
                                                     float* __restrict__ avec,
                                                     float* __restrict__ bvec,
                                                     int* __restrict__ bar,
                                                     const float* __restrict__ alpha) {
    int blk   = blockIdx.x;
    int batch = blk & 7;           // XCD id under round-robin dispatch
    int rb    = blk >> 3;
    int tid   = threadIdx.x;
    int seg   = tid & 15;
    int row   = tid >> 4;          // row within the 64-row shard
    int grow  = rb * 64 + row;     // global row

    __shared__ __align__(16) unsigned char Ks[64 * 2048];   // 128 KB fp8 shard
    __shared__ float xs[16 * 132];                          // padded x stage
    __shared__ float wsum[16];

    {
        const int4* gsrc = (const int4*)(K8 + ((size_t)batch * NN + (size_t)rb * 64) * NN);
#pragma unroll
        for (int q = 0; q < 8; q++) {
            int idx = q * 1024 + tid;
            int4 v = gsrc[idx];
            int g = idx * 16;
            int r_ = g >> 11, bir = g & 2047;
            *(int4*)&Ks[r_ * 2048 + (bir ^ (((bir >> 7) & 7) << 4))] = v;
        }
    }   // first pass's __syncthreads() covers this staging

    float* av = avec + (size_t)batch * VSTR;
    float* bv = bvec + (size_t)batch * VSTR;
    int*   gbar = bar + batch * GRP;
    float E    = __expf(alpha[0]);
    float binA = 0.f, binB = 1.0f;
    int   ep   = 0;
    const float4* xp4 = (const float4*)(xs + seg * 132);
    const int kbase = row * 2048;
    const int sb    = seg * 128;
    const int sx    = (seg & 7) << 4;

#define MAC16(KI, ACC)                                                          \
    {                                                                           \
        int4 kv = *(const int4*)&Ks[kbase + ((sb + (KI) * 16) ^ sx)];           \
        float4 xa = xp4[(KI) * 4 + 0], xb = xp4[(KI) * 4 + 1];                  \
        float4 xc = xp4[(KI) * 4 + 2], xd = xp4[(KI) * 4 + 3];                  \
        f32x2 p0 = __builtin_amdgcn_cvt_pk_f32_fp8(kv.x, false);                \
        f32x2 p1 = __builtin_amdgcn_cvt_pk_f32_fp8(kv.x, true);                 \
        f32x2 p2 = __builtin_amdgcn_cvt_pk_f32_fp8(kv.y, false);                \
        f32x2 p3 = __builtin_amdgcn_cvt_pk_f32_fp8(kv.y, true);                 \
        f32x2 p4 = __builtin_amdgcn_cvt_pk_f32_fp8(kv.z, false);                \
        f32x2 p5 = __builtin_amdgcn_cvt_pk_f32_fp8(kv.z, true);                 \
        f32x2 p6 = __builtin_amdgcn_cvt_pk_f32_fp8(kv.w, false);                \
        f32x2 p7 = __builtin_amdgcn_cvt_pk_f32_fp8(kv.w, true);                 \
        ACC = fmaf(p0.x, xa.x, ACC); ACC = fmaf(p0.y, xa.y, ACC);               \
        ACC = fmaf(p1.x, xa.z, ACC); ACC = fmaf(p1.y, xa.w, ACC);               \
        ACC = fmaf(p2.x, xb.x, ACC); ACC = fmaf(p2.y, xb.y, ACC);               \
        ACC = fmaf(p3.x, xb.z, ACC); ACC = fmaf(p3.y, xb.w, ACC);               \
        ACC = fmaf(p4.x, xc.x, ACC); ACC = fmaf(p4.y, xc.y, ACC);               \
        ACC = fmaf(p5.x, xc.z, ACC); ACC = fmaf(p5.y, xc.w, ACC);               \
        ACC = fmaf(p6.x, xd.x, ACC); ACC = fmaf(p6.y, xd.y, ACC);               \
        ACC = fmaf(p7.x, xd.z, ACC); ACC = fmaf(p7.y, xd.w, ACC);               \
    }

#define SINK_PASS(XIN, XOUT, BIN_IN, BIN_OUT, LAST)                             \
    {                                                                           \
        float sv;                                                               \
        {   /* stage XIN via sc1 atomic loads (coherence-point reads) */        \
            float v0 = __hip_atomic_load((XIN) + 2 * tid, __ATOMIC_RELAXED,     \
                                         __HIP_MEMORY_SCOPE_AGENT);             \
            float v1 = __hip_atomic_load((XIN) + 2 * tid + 1, __ATOMIC_RELAXED, \
                                         __HIP_MEMORY_SCOPE_AGENT);             \
            int j = tid * 2;                                                    \
            float* d = xs + ((j >> 7) * 132 + (j & 127));                       \
            d[0] = v0; d[1] = v1;                                               \
            sv = v0 + v1;                                                       \
        }                                                                       \
        sv += __shfl_xor(sv, 1);  sv += __shfl_xor(sv, 2);                      \
        sv += __shfl_xor(sv, 4);  sv += __shfl_xor(sv, 8);                      \
        sv += __shfl_xor(sv, 16); sv += __shfl_xor(sv, 32);                     \
        if ((tid & 63) == 0) wsum[tid >> 6] = sv;                               \
        __syncthreads();                                                        \
        float S_cur = 0.f;                                                      \
        _Pragma("unroll")                                                       \
        for (int w2 = 0; w2 < 16; w2++) S_cur += wsum[w2];                      \
        float dot0 = 0.f, dot1 = 0.f;                                           \
        MAC16(0, dot0) MAC16(1, dot1) MAC16(2, dot0) MAC16(3, dot1)             \
        MAC16(4, dot0) MAC16(5, dot1) MAC16(6, dot0) MAC16(7, dot1)             \
        float dot = dot0 + dot1;                                                \
        dot += __shfl_xor(dot, 1);                                              \
        dot += __shfl_xor(dot, 2);                                              \
        dot += __shfl_xor(dot, 4);                                              \
        dot += __shfl_xor(dot, 8);                                              \
        float val = (1.0f / 4096.0f) / (dot + E * (BIN_IN));                    \
        BIN_OUT = 0.5f / (E * (S_cur + (BIN_IN)));                              \
        if ((tid & 15) == 0)                                                    \
            __hip_atomic_store(&(XOUT)[grow], val, __ATOMIC_RELAXED,            \
                               __HIP_MEMORY_SCOPE_AGENT);                       \
        __syncthreads();   /* vmcnt(0) drain: val stores complete (sc1) */      \
        if (!(LAST)) {                                                          \
            ep++;                                                               \
            if (tid == 0)                                                       \
                __hip_atomic_store(&gbar[rb], ep, __ATOMIC_RELAXED,             \
                                   __HIP_MEMORY_SCOPE_AGENT);                   \
            if (tid < GRP) {                                                    \
                while (__hip_atomic_load(&gbar[tid], __ATOMIC_RELAXED,          \
                                         __HIP_MEMORY_SCOPE_AGENT) < ep)        \
                    __builtin_amdgcn_s_sleep(1);                                \
            }                                                                   \
            __syncthreads();                                                    \
        }                                                                       \
    }

    for (int it2 = 0; it2 < NITER; it2++) {
        SINK_PASS(bv, av, binB, binA, false);
        SINK_PASS(av, bv, binA, binB, (it2 == NITER - 1));
    }
#undef SINK_PASS
#undef MAC16

    if (tid == 0) { av[NN] = binA; bv[NN] = binB; }
}

// fp32 fallback pass (K in d_out, stride NP1) for ws-too-small case.
__global__ __launch_bounds__(256) void sink_pass_f32(const float* __restrict__ K,
                                                     const float* __restrict__ xin,
                                                     float* __restrict__ xout,
                                                     const float* __restrict__ sum_in,
                                                     float* __restrict__ sum_out,
                                                     const float* __restrict__ alpha) {
    int bb = blockIdx.y;
    int i0 = blockIdx.x * 16;
    __shared__ float xsl[NN];
    __shared__ float rowa[16];
    const float* xinb = xin + (size_t)bb * VSTR;
    int t = threadIdx.x;
    for (int j = t; j < NN; j += 256) xsl[j] = xinb[j];
    __syncthreads();
    float E  = __expf(alpha[0]);
    float xN = xinb[NN];
    int wave = t >> 6, lane = t & 63;
    const float* Kb = K + (size_t)bb * NP1 * NP1;
    for (int r = wave; r < 16; r += 4) {
        int i = i0 + r;
        const float* rowp = Kb + (size_t)i * NP1;
        float acc = 0.f;
        for (int j = lane; j < NN; j += 64) acc = fmaf(rowp[j], xsl[j], acc);
#pragma unroll
        for (int off = 32; off >= 1; off >>= 1) acc += __shfl_xor(acc, off);
        if (lane == 0) {
            float v = (1.0f / 4096.0f) / (acc + E * xN);
            xout[(size_t)bb * VSTR + i] = v;
            rowa[r] = v;
        }
    }
    __syncthreads();
    if (t == 0) {
        float s = 0.f;
#pragma unroll
        for (int r = 0; r < 16; r++) s += rowa[r];
        atomicAdd(sum_out + bb, s);
        if (blockIdx.x == 0) xout[(size_t)bb * VSTR + NN] = 0.5f / (E * (sum_in[bb] + xN));
    }
}

// out[i,j] = K*a_i*b_j*4096*cost (i,j<N), bins use E. FP8: K from K8; else in-place.
template <bool FP8>
__global__ __launch_bounds__(256) void final_kernel(float* __restrict__ out,
                                                    const unsigned char* __restrict__ K8,
                                                    const float* __restrict__ avec,
                                                    const float* __restrict__ bvec,
                                                    const float* __restrict__ pos,
                                                    const float* __restrict__ alpha) {
    int bb = blockIdx.y;
    int i0 = blockIdx.x * 16;
    __shared__ float as_[16], ys[16], xs2[16];
    int t = threadIdx.x;
    if (t < 16) {
        int i = i0 + t;
        as_[t] = (i < NP1) ? avec[(size_t)bb * VSTR + i] : 0.f;
        if (i < NN) {
            ys[t]  = pos[((size_t)bb * NN + i) * 2 + 0];
            xs2[t] = pos[((size_t)bb * NN + i) * 2 + 1];
        } else {
            ys[t] = 1e9f; xs2[t] = 1e9f;
        }
    }
    __syncthreads();
    float E = __expf(alpha[0]);
    float* outb = out + (size_t)bb * NP1 * NP1;
    const unsigned char* K8b = K8 + (size_t)bb * NN * NN;
    for (int j = t; j < NP1; j += 256) {
        float bj = bvec[(size_t)bb * VSTR + j];
        bool jin = (j < NN);
        float yj = 0.f, xj = 0.f;
        if (jin) {
            yj = pos[((size_t)bb * NN + j) * 2 + 0];
            xj = pos[((size_t)bb * NN + j) * 2 + 1];
        }
#pragma unroll 1
        for (int r = 0; r < 16; r++) {
            int i = i0 + r;
            if (i >= NP1) break;
            size_t idx = (size_t)i * NP1 + j;
            float v;
            if (i < NN && jin) {
                float Kv;
                if constexpr (FP8)
                    Kv = __builtin_amdgcn_cvt_f32_fp8((int)K8b[(size_t)i * NN + j], 0);
                else
                    Kv = outb[idx];
                bool c = (fabsf(ys[r] - yj) <= 0.1f) && (fabsf(xs2[r] - xj) <= 0.1f);
                v = c ? Kv * as_[r] * bj * 4096.0f : 0.0f;
            } else {
                v = E * as_[r] * bj * 4096.0f;
            }
            outb[idx] = v;
        }
    }
}

extern "C" void kernel_launch(void* const* d_in, const int* in_sizes, int n_in,
                              void* d_out, int out_size, void* d_ws, size_t ws_size,
                              hipStream_t stream) {
    const float* F     = (const float*)d_in[0];  // (B, D, N)
    const float* pos   = (const float*)d_in[1];  // (B, N, 2)
    const float* alpha = (const float*)d_in[3];  // (1,)
    float* out = (float*)d_out;
    float* ws  = (float*)d_ws;

    float* avec = ws;
    float* bvec = ws + BN * VSTR;
    float* sums = ws + 2 * BN * VSTR;                 // 41*BN floats (fallback path)
    int*   bar  = (int*)(sums + 41 * BN);             // BN x GRP arrival slots
    float* psum = (float*)(bar + BN * GRP);           // kept for layout stability
    unsigned char* K8  = (unsigned char*)(psum + 2 * BN * GRP);  // 33.5 MB fp8
    unsigned char* F16 = K8 + (size_t)BN * NN * NN;              // 8.4 MB bf16

    size_t need = (size_t)(2 * BN * VSTR + 41 * BN + 3 * BN * GRP) * 4
                + (size_t)BN * NN * NN + (size_t)BN * NN * DD * 2;
    bool fp8 = (ws_size >= need);

    hipLaunchKernelGGL(init_kernel, dim3(64), dim3(256), 0, stream, bvec, BN * VSTR,
                       sums, bar);

    if (fp8) {
        hipLaunchKernelGGL(f_to_bf16, dim3(NN / 64, DD / 64, BN), dim3(256), 0, stream,
                           F, F16);
        hipLaunchKernelGGL(build_k3, dim3(136, 1, BN), dim3(256), 0, stream, F16, K8);
        // Plain launch (NOT cooperative): co-residency guaranteed by LDS
        // capacity (1 block/CU, grid == CU count); kernel uses only own
        // flag barriers, no cg grid_sync.
        hipLaunchKernelGGL(sink_persist, dim3(NBLK), dim3(1024), 0, stream,
                           K8, avec, bvec, bar, alpha);
        hipLaunchKernelGGL((final_kernel<true>), dim3((NP1 + 15) / 16, BN), dim3(256), 0,
                           stream, out, K8, avec, bvec, pos, alpha);
    } else {
        hipLaunchKernelGGL(build_k_f32, dim3(32, 32, BN), dim3(256), 0, stream, F, out);
        const float* xin = bvec;
        float* xout = avec;
        for (int p = 1; p <= 2 * NITER; p++) {
            hipLaunchKernelGGL(sink_pass_f32, dim3(NN / 16, BN), dim3(256), 0, stream,
                               out, xin, xout, sums + (p - 1) * BN, sums + p * BN, alpha);
            float* tmp = (float*)xin; xin = xout; xout = tmp;
        }
        hipLaunchKernelGGL((final_kernel<false>), dim3((NP1 + 15) / 16, BN), dim3(256), 0,
                           stream, out, K8, avec, bvec, pos, alpha);
    }
}

// Round 20
// 274.138 us; speedup vs baseline: 1.3405x; 1.1830x over previous
//
#include <hip/hip_runtime.h>
#include <math.h>

#define BN    8
#define NN    2048
#define NP1   2049
#define VSTR  2056   // padded a/b vector stride (floats), 16B-aligned rows
#define DD    256
#define NITER 20
#define NBLK  256    // persistent grid size, 1 block/CU (LDS-capacity-pinned)
#define GRP   32     // blocks per batch (independent barrier group)

typedef float f32x2 __attribute__((ext_vector_type(2)));
typedef float f32x4_t __attribute__((ext_vector_type(4)));
typedef short short8 __attribute__((ext_vector_type(8)));

// ws layout: a[BN*VSTR] f32 | b[BN*VSTR] f32 | sums[41*BN] f32 | bar[BN*GRP] i32 |
//            psum[2*BN*GRP] f32 (unused) | K8[BN*NN*NN] fp8 | F16[BN*NN*DD] bf16

__global__ void init_kernel(float* __restrict__ bvec, int nb, float* __restrict__ sums,
                            int* __restrict__ bar) {
    int tid = blockIdx.x * blockDim.x + threadIdx.x;
    int stride = gridDim.x * blockDim.x;
    for (int i = tid; i < nb; i += stride) bvec[i] = 1.0f;            // v0 = 0 -> b = 1
    for (int i = tid; i < 41 * BN; i += stride) sums[i] = (i < BN) ? (float)NN : 0.0f;
    if (tid < BN * GRP) bar[tid] = 0;
}

__device__ __forceinline__ unsigned short f2bf(float f) {
    unsigned u = __builtin_bit_cast(unsigned, f);
    return (unsigned short)((u + 0x7fffu + ((u >> 16) & 1u)) >> 16);   // RNE
}

// Pre-pass: F (B,D,N) f32 -> F16 (B,N,D) bf16, LDS-tiled 64x64 transpose.
__global__ __launch_bounds__(256) void f_to_bf16(const float* __restrict__ F,
                                                 unsigned char* __restrict__ F16) {
    int x0 = blockIdx.x * 64, k0 = blockIdx.y * 64, bb = blockIdx.z;
    __shared__ unsigned short tile[64][68];    // 68-pad: 8B-aligned rows
    int t = threadIdx.x;
    const float* Fb = F + (size_t)bb * DD * NN;
#pragma unroll
    for (int q = 0; q < 16; q++) {
        int idx = q * 256 + t;
        int kk = idx >> 6, xx = idx & 63;
        tile[xx][kk] = f2bf(Fb[(size_t)(k0 + kk) * NN + x0 + xx]);
    }
    __syncthreads();
    int r = t >> 2, c = t & 3;                 // row, 16-elem chunk
    const unsigned long long* src = (const unsigned long long*)&tile[r][c * 16];
    unsigned long long v0 = src[0], v1 = src[1], v2 = src[2], v3 = src[3];
    unsigned char* dst = F16 + (((size_t)bb * NN + x0 + r) * DD + k0) * 2 + c * 32;
    ((unsigned long long*)dst)[0] = v0;
    ((unsigned long long*)dst)[1] = v1;
    ((unsigned long long*)dst)[2] = v2;
    ((unsigned long long*)dst)[3] = v3;
}

// build_k v4: symmetric-pair MFMA build (R18, verified). 136 upper-triangle
// tile pairs; each block emits tile (i,j) row-major + mirror (j,i) via the
// col-major Cm bounce. Cm aliases Ab/Bb.
__global__ __launch_bounds__(256) void build_k3(const unsigned char* __restrict__ F16,
                                                unsigned char* __restrict__ K8) {
    int idx = blockIdx.x, ti = 0;
    while (idx >= 16 - ti) { idx -= 16 - ti; ti++; }
    int tj = ti + idx;
    int bb = blockIdx.z;
    int i0 = ti * 128, j0 = tj * 128;
    const unsigned char* F16b = F16 + (size_t)bb * NN * DD * 2;

    __shared__ __align__(16) unsigned char Smem[128 * 80 * 2];   // 20480 B
    unsigned char* Ab = Smem;                    // [x][k] bf16, 80B rows
    unsigned char* Bb = Smem + 128 * 80;
    unsigned char* Cm = Smem;                    // ALIAS: col-major fp8 [c][i]

    int t = threadIdx.x;
    int w = t >> 6, l = t & 63;
    int wr = w >> 1, wc = w & 1;           // wave grid 2x2 -> 64x64 per wave
    int g = l >> 4, c16 = l & 15;

    f32x4_t acc[4][4];
#pragma unroll
    for (int r = 0; r < 4; r++)
#pragma unroll
        for (int c = 0; c < 4; c++) acc[r][c] = (f32x4_t){0.f, 0.f, 0.f, 0.f};

    int xr = t >> 2, q4 = t & 3;
    uint4 va0 = *(const uint4*)(F16b + ((size_t)(i0 + xr) * DD) * 2 + q4 * 16);
    uint4 va1 = *(const uint4*)(F16b + ((size_t)(i0 + 64 + xr) * DD) * 2 + q4 * 16);
    uint4 vb0 = *(const uint4*)(F16b + ((size_t)(j0 + xr) * DD) * 2 + q4 * 16);
    uint4 vb1 = *(const uint4*)(F16b + ((size_t)(j0 + 64 + xr) * DD) * 2 + q4 * 16);

    for (int k0 = 0; k0 < DD; k0 += 32) {
        *(uint4*)(Ab + xr * 80 + q4 * 16)        = va0;
        *(uint4*)(Ab + (64 + xr) * 80 + q4 * 16) = va1;
        *(uint4*)(Bb + xr * 80 + q4 * 16)        = vb0;
        *(uint4*)(Bb + (64 + xr) * 80 + q4 * 16) = vb1;
        __syncthreads();

        if (k0 + 32 < DD) {
            int kn = (k0 + 32) * 2;
            va0 = *(const uint4*)(F16b + (size_t)(i0 + xr) * DD * 2 + kn + q4 * 16);
            va1 = *(const uint4*)(F16b + (size_t)(i0 + 64 + xr) * DD * 2 + kn + q4 * 16);
            vb0 = *(const uint4*)(F16b + (size_t)(j0 + xr) * DD * 2 + kn + q4 * 16);
            vb1 = *(const uint4*)(F16b + (size_t)(j0 + 64 + xr) * DD * 2 + kn + q4 * 16);
        }

        short8 af[4], bf_[4];
#pragma unroll
        for (int rf = 0; rf < 4; rf++)
            af[rf] = *(const short8*)(Ab + (wr * 64 + rf * 16 + c16) * 80 + g * 16);
#pragma unroll
        for (int cf = 0; cf < 4; cf++)
            bf_[cf] = *(const short8*)(Bb + (wc * 64 + cf * 16 + c16) * 80 + g * 16);
#pragma unroll
        for (int rf = 0; rf < 4; rf++)
#pragma unroll
            for (int cf = 0; cf < 4; cf++)
                acc[rf][cf] = __builtin_amdgcn_mfma_f32_16x16x32_bf16(
                    af[rf], bf_[cf], acc[rf][cf], 0, 0, 0);
        __syncthreads();
    }

#pragma unroll
    for (int rf = 0; rf < 4; rf++) {
#pragma unroll
        for (int cf = 0; cf < 4; cf++) {
            int ib = wr * 64 + rf * 16 + g * 4;
            int jl = wc * 64 + cf * 16 + c16;
            float v[4];
#pragma unroll
            for (int r = 0; r < 4; r++) {
                float e = __expf(acc[rf][cf][r] * 0.0625f);   // 1/sqrt(256)
                if (i0 + ib + r == j0 + jl) e = 0.0f;
                v[r] = e;
            }
            unsigned wd = __builtin_amdgcn_cvt_pk_fp8_f32(v[0], v[1], 0, false);
            wd = __builtin_amdgcn_cvt_pk_fp8_f32(v[2], v[3], wd, true);
            *(unsigned*)(Cm + jl * 132 + ib) = wd;
        }
    }
    __syncthreads();

    unsigned char* K8b = K8 + (size_t)bb * NN * NN;
    int il = t >> 1, hh = t & 1;
    {
        unsigned wrow[16];
#pragma unroll
        for (int cq = 0; cq < 16; cq++) {
            int cb = hh * 64 + cq * 4;
            unsigned b0 = Cm[(cb + 0) * 132 + il];
            unsigned b1 = Cm[(cb + 1) * 132 + il];
            unsigned b2 = Cm[(cb + 2) * 132 + il];
            unsigned b3 = Cm[(cb + 3) * 132 + il];
            wrow[cq] = b0 | (b1 << 8) | (b2 << 16) | (b3 << 24);
        }
        uint4* dst = (uint4*)(K8b + (size_t)(i0 + il) * NN + j0 + hh * 64);
#pragma unroll
        for (int qq = 0; qq < 4; qq++) {
            uint4 u; u.x = wrow[qq * 4]; u.y = wrow[qq * 4 + 1];
            u.z = wrow[qq * 4 + 2]; u.w = wrow[qq * 4 + 3];
            dst[qq] = u;
        }
    }
    if (tj > ti) {
        const uint4* srcp = (const uint4*)(Cm + il * 132 + hh * 64);
        uint4 u0 = srcp[0], u1 = srcp[1], u2 = srcp[2], u3 = srcp[3];
        uint4* dst = (uint4*)(K8b + (size_t)(j0 + il) * NN + i0 + hh * 64);
        dst[0] = u0; dst[1] = u1; dst[2] = u2; dst[3] = u3;
    }
}

// fp32 fallback build (writes into out, stride NP1). Symmetric-half as before.
__global__ __launch_bounds__(256) void build_k_f32(const float* __restrict__ F,
                                                   float* __restrict__ out) {
    int ti = blockIdx.x, tj = blockIdx.y, bb = blockIdx.z;
    if (tj < ti) return;
    __shared__ float As[32][64];
    __shared__ float Bs[32][64];
    int t  = threadIdx.x;
    int tx = t & 15, ty = t >> 4;
    float acc[4][4] = {};
    const float* Fb = F + (size_t)bb * DD * NN;
    int i0 = ti * 64, j0 = tj * 64;
    for (int k0 = 0; k0 < DD; k0 += 32) {
#pragma unroll
        for (int v = 0; v < 2; v++) {
            int f = t + 256 * v;
            int row = f >> 4, c4 = (f & 15) * 4;
            *(float4*)&As[row][c4] = *(const float4*)&Fb[(size_t)(k0 + row) * NN + i0 + c4];
            *(float4*)&Bs[row][c4] = *(const float4*)&Fb[(size_t)(k0 + row) * NN + j0 + c4];
        }
        __syncthreads();
#pragma unroll
        for (int k = 0; k < 32; k++) {
            float4 av = *(float4*)&As[k][ty * 4];
            float4 bv = *(float4*)&Bs[k][tx * 4];
            float ar[4] = {av.x, av.y, av.z, av.w};
            float br[4] = {bv.x, bv.y, bv.z, bv.w};
#pragma unroll
            for (int r = 0; r < 4; r++)
#pragma unroll
                for (int c = 0; c < 4; c++)
                    acc[r][c] = fmaf(ar[r], br[c], acc[r][c]);
        }
        __syncthreads();
    }
#pragma unroll
    for (int r = 0; r < 4; r++) {
        int i = i0 + ty * 4 + r;
#pragma unroll
        for (int c = 0; c < 4; c++) {
            int j = j0 + tx * 4 + c;
            float Kv = (i == j) ? 0.0f : __expf(acc[r][c] * 0.0625f);
            float* outb = out + (size_t)bb * NP1 * NP1;
            outb[(size_t)i * NP1 + j] = Kv;
            if (tj > ti) outb[(size_t)j * NP1 + i] = Kv;
        }
    }
}

// Persistent Sinkhorn + FUSED FINAL. K shard in LDS; fence-free sc1 exchange
// (R15); plain launch (R19, co-residency by LDS capacity). New in R20: the
// final rescale writes out[] directly from the LDS-resident K shard — saves
// the separate final_kernel's K8 re-read + launch gap. pos staged to LDS
// (+16 KB -> 156 KB, still 1 block/CU); block's own a-row values cached in
// ava[64] during the last a-pass; one extra flag barrier before the epilogue.
__global__ __launch_bounds__(1024) void sink_persist(const unsigned char* __restrict__ K8,
                                                     float* __restrict__ avec,
                                                     float* __restrict__ bvec,
                                                     int* __restrict__ bar,
                                                     const float* __restrict__ alpha,
                                                     const float* __restrict__ pos,
                                                     float* __restrict__ outp) {
    int blk   = blockIdx.x;
    int batch = blk & 7;           // XCD id under round-robin dispatch
    int rb    = blk >> 3;
    int tid   = threadIdx.x;
    int seg   = tid & 15;
    int row   = tid >> 4;          // row within the 64-row shard
    int grow  = rb * 64 + row;     // global row

    __shared__ __align__(16) unsigned char Ks[64 * 2048];   // 128 KB fp8 shard
    __shared__ float xs[16 * 132];                          // padded x stage
    __shared__ float wsum[16];
    __shared__ float ava[64];                               // this block's a rows
    __shared__ float posy[NN], posx[NN];                    // batch positions

    {
        const int4* gsrc = (const int4*)(K8 + ((size_t)batch * NN + (size_t)rb * 64) * NN);
#pragma unroll
        for (int q = 0; q < 8; q++) {
            int idx = q * 1024 + tid;
            int4 v = gsrc[idx];
            int g = idx * 16;
            int r_ = g >> 11, bir = g & 2047;
            *(int4*)&Ks[r_ * 2048 + (bir ^ (((bir >> 7) & 7) << 4))] = v;
        }
        const float2* pp2 = (const float2*)(pos + (size_t)batch * NN * 2);
        float2 p0 = pp2[tid];
        float2 p1 = pp2[tid + 1024];
        posy[tid] = p0.x;        posx[tid] = p0.y;
        posy[tid + 1024] = p1.x; posx[tid + 1024] = p1.y;
    }   // first pass's __syncthreads() covers this staging

    float* av = avec + (size_t)batch * VSTR;
    float* bv = bvec + (size_t)batch * VSTR;
    int*   gbar = bar + batch * GRP;
    float E    = __expf(alpha[0]);
    float binA = 0.f, binB = 1.0f;
    int   ep   = 0;
    const float4* xp4 = (const float4*)(xs + seg * 132);
    const int kbase = row * 2048;
    const int sb    = seg * 128;
    const int sx    = (seg & 7) << 4;

#define MAC16(KI, ACC)                                                          \
    {                                                                           \
        int4 kv = *(const int4*)&Ks[kbase + ((sb + (KI) * 16) ^ sx)];           \
        float4 xa = xp4[(KI) * 4 + 0], xb = xp4[(KI) * 4 + 1];                  \
        float4 xc = xp4[(KI) * 4 + 2], xd = xp4[(KI) * 4 + 3];                  \
        f32x2 p0 = __builtin_amdgcn_cvt_pk_f32_fp8(kv.x, false);                \
        f32x2 p1 = __builtin_amdgcn_cvt_pk_f32_fp8(kv.x, true);                 \
        f32x2 p2 = __builtin_amdgcn_cvt_pk_f32_fp8(kv.y, false);                \
        f32x2 p3 = __builtin_amdgcn_cvt_pk_f32_fp8(kv.y, true);                 \
        f32x2 p4 = __builtin_amdgcn_cvt_pk_f32_fp8(kv.z, false);                \
        f32x2 p5 = __builtin_amdgcn_cvt_pk_f32_fp8(kv.z, true);                 \
        f32x2 p6 = __builtin_amdgcn_cvt_pk_f32_fp8(kv.w, false);                \
        f32x2 p7 = __builtin_amdgcn_cvt_pk_f32_fp8(kv.w, true);                 \
        ACC = fmaf(p0.x, xa.x, ACC); ACC = fmaf(p0.y, xa.y, ACC);               \
        ACC = fmaf(p1.x, xa.z, ACC); ACC = fmaf(p1.y, xa.w, ACC);               \
        ACC = fmaf(p2.x, xb.x, ACC); ACC = fmaf(p2.y, xb.y, ACC);               \
        ACC = fmaf(p3.x, xb.z, ACC); ACC = fmaf(p3.y, xb.w, ACC);               \
        ACC = fmaf(p4.x, xc.x, ACC); ACC = fmaf(p4.y, xc.y, ACC);               \
        ACC = fmaf(p5.x, xc.z, ACC); ACC = fmaf(p5.y, xc.w, ACC);               \
        ACC = fmaf(p6.x, xd.x, ACC); ACC = fmaf(p6.y, xd.y, ACC);               \
        ACC = fmaf(p7.x, xd.z, ACC); ACC = fmaf(p7.y, xd.w, ACC);               \
    }

#define SINK_PASS(XIN, XOUT, BIN_IN, BIN_OUT, SAVEA, LAST)                      \
    {                                                                           \
        float sv;                                                               \
        {   /* stage XIN via sc1 atomic loads (coherence-point reads) */        \
            float v0 = __hip_atomic_load((XIN) + 2 * tid, __ATOMIC_RELAXED,     \
                                         __HIP_MEMORY_SCOPE_AGENT);             \
            float v1 = __hip_atomic_load((XIN) + 2 * tid + 1, __ATOMIC_RELAXED, \
                                         __HIP_MEMORY_SCOPE_AGENT);             \
            int j = tid * 2;                                                    \
            float* d = xs + ((j >> 7) * 132 + (j & 127));                       \
            d[0] = v0; d[1] = v1;                                               \
            sv = v0 + v1;                                                       \
        }                                                                       \
        sv += __shfl_xor(sv, 1);  sv += __shfl_xor(sv, 2);                      \
        sv += __shfl_xor(sv, 4);  sv += __shfl_xor(sv, 8);                      \
        sv += __shfl_xor(sv, 16); sv += __shfl_xor(sv, 32);                     \
        if ((tid & 63) == 0) wsum[tid >> 6] = sv;                               \
        __syncthreads();                                                        \
        float S_cur = 0.f;                                                      \
        _Pragma("unroll")                                                       \
        for (int w2 = 0; w2 < 16; w2++) S_cur += wsum[w2];                      \
        float dot0 = 0.f, dot1 = 0.f;                                           \
        MAC16(0, dot0) MAC16(1, dot1) MAC16(2, dot0) MAC16(3, dot1)             \
        MAC16(4, dot0) MAC16(5, dot1) MAC16(6, dot0) MAC16(7, dot1)             \
        float dot = dot0 + dot1;                                                \
        dot += __shfl_xor(dot, 1);                                              \
        dot += __shfl_xor(dot, 2);                                              \
        dot += __shfl_xor(dot, 4);                                              \
        dot += __shfl_xor(dot, 8);                                              \
        float val = (1.0f / 4096.0f) / (dot + E * (BIN_IN));                    \
        BIN_OUT = 0.5f / (E * (S_cur + (BIN_IN)));                              \
        if ((tid & 15) == 0) {                                                  \
            __hip_atomic_store(&(XOUT)[grow], val, __ATOMIC_RELAXED,            \
                               __HIP_MEMORY_SCOPE_AGENT);                       \
            if (SAVEA) ava[tid >> 4] = val;                                     \
        }                                                                       \
        __syncthreads();   /* vmcnt(0) drain: val stores complete (sc1) */      \
        if (!(LAST)) {                                                          \
            ep++;                                                               \
            if (tid == 0)                                                       \
                __hip_atomic_store(&gbar[rb], ep, __ATOMIC_RELAXED,             \
                                   __HIP_MEMORY_SCOPE_AGENT);                   \
            if (tid < GRP) {                                                    \
                while (__hip_atomic_load(&gbar[tid], __ATOMIC_RELAXED,          \
                                         __HIP_MEMORY_SCOPE_AGENT) < ep)        \
                    __builtin_amdgcn_s_sleep(1);                                \
            }                                                                   \
            __syncthreads();                                                    \
        }                                                                       \
    }

    for (int it2 = 0; it2 < NITER; it2++) {
        SINK_PASS(bv, av, binB, binA, (it2 == NITER - 1), false);
        SINK_PASS(av, bv, binA, binB, false, (it2 == NITER - 1));
    }
#undef SINK_PASS
#undef MAC16

    if (tid == 0) { av[NN] = binA; bv[NN] = binB; }

    // ---- fused final epilogue ----
    // barrier: all blocks' final bv stores visible
    ep++;
    if (tid == 0)
        __hip_atomic_store(&gbar[rb], ep, __ATOMIC_RELAXED, __HIP_MEMORY_SCOPE_AGENT);
    if (tid < GRP) {
        while (__hip_atomic_load(&gbar[tid], __ATOMIC_RELAXED,
                                 __HIP_MEMORY_SCOPE_AGENT) < ep)
            __builtin_amdgcn_s_sleep(1);
    }
    __syncthreads();
    // stage full bv into xs (padded layout)
    {
        float v0 = __hip_atomic_load(bv + 2 * tid, __ATOMIC_RELAXED,
                                     __HIP_MEMORY_SCOPE_AGENT);
        float v1 = __hip_atomic_load(bv + 2 * tid + 1, __ATOMIC_RELAXED,
                                     __HIP_MEMORY_SCOPE_AGENT);
        int j = tid * 2;
        float* d = xs + ((j >> 7) * 132 + (j & 127));
        d[0] = v0; d[1] = v1;
    }
    __syncthreads();

    float* outb = outp + (size_t)batch * NP1 * NP1;
    // thread t covers cols c0 = t and c1 = t + 1024, all 64 shard rows
    int c0 = tid, c1 = tid + 1024;
    int lo0 = c0 ^ (((c0 >> 7) & 7) << 4);
    int lo1 = c1 ^ (((c1 >> 7) & 7) << 4);
    float b0 = xs[(c0 >> 7) * 132 + (c0 & 127)];
    float b1 = xs[(c1 >> 7) * 132 + (c1 & 127)];
    float y0 = posy[c0], x0 = posx[c0];
    float y1 = posy[c1], x1 = posx[c1];
#pragma unroll 4
    for (int r = 0; r < 64; r++) {
        int gr = rb * 64 + r;
        float ai = ava[r];
        float yi = posy[gr], xi = posx[gr];
        float K0 = __builtin_amdgcn_cvt_f32_fp8((int)Ks[r * 2048 + lo0], 0);
        float K1 = __builtin_amdgcn_cvt_f32_fp8((int)Ks[r * 2048 + lo1], 0);
        bool cc0 = (fabsf(yi - y0) <= 0.1f) && (fabsf(xi - x0) <= 0.1f);
        bool cc1 = (fabsf(yi - y1) <= 0.1f) && (fabsf(xi - x1) <= 0.1f);
        outb[(size_t)gr * NP1 + c0] = cc0 ? K0 * ai * b0 * 4096.0f : 0.0f;
        outb[(size_t)gr * NP1 + c1] = cc1 ? K1 * ai * b1 * 4096.0f : 0.0f;
    }
    // bin column (j = NN) for this block's rows
    if (tid < 64)
        outb[(size_t)(rb * 64 + tid) * NP1 + NN] = E * ava[tid] * binB * 4096.0f;
    // bin row (i = NN) + corner, by the rb==0 block of each batch
    if (rb == 0) {
        outb[(size_t)NN * NP1 + c0] = E * binA * b0 * 4096.0f;
        outb[(size_t)NN * NP1 + c1] = E * binA * b1 * 4096.0f;
        if (tid == 0) outb[(size_t)NN * NP1 + NN] = E * binA * binB * 4096.0f;
    }
}

// fp32 fallback pass (K in d_out, stride NP1) for ws-too-small case.
__global__ __launch_bounds__(256) void sink_pass_f32(const float* __restrict__ K,
                                                     const float* __restrict__ xin,
                                                     float* __restrict__ xout,
                                                     const float* __restrict__ sum_in,
                                                     float* __restrict__ sum_out,
                                                     const float* __restrict__ alpha) {
    int bb = blockIdx.y;
    int i0 = blockIdx.x * 16;
    __shared__ float xsl[NN];
    __shared__ float rowa[16];
    const float* xinb = xin + (size_t)bb * VSTR;
    int t = threadIdx.x;
    for (int j = t; j < NN; j += 256) xsl[j] = xinb[j];
    __syncthreads();
    float E  = __expf(alpha[0]);
    float xN = xinb[NN];
    int wave = t >> 6, lane = t & 63;
    const float* Kb = K + (size_t)bb * NP1 * NP1;
    for (int r = wave; r < 16; r += 4) {
        int i = i0 + r;
        const float* rowp = Kb + (size_t)i * NP1;
        float acc = 0.f;
        for (int j = lane; j < NN; j += 64) acc = fmaf(rowp[j], xsl[j], acc);
#pragma unroll
        for (int off = 32; off >= 1; off >>= 1) acc += __shfl_xor(acc, off);
        if (lane == 0) {
            float v = (1.0f / 4096.0f) / (acc + E * xN);
            xout[(size_t)bb * VSTR + i] = v;
            rowa[r] = v;
        }
    }
    __syncthreads();
    if (t == 0) {
        float s = 0.f;
#pragma unroll
        for (int r = 0; r < 16; r++) s += rowa[r];
        atomicAdd(sum_out + bb, s);
        if (blockIdx.x == 0) xout[(size_t)bb * VSTR + NN] = 0.5f / (E * (sum_in[bb] + xN));
    }
}

// fp32-fallback final: out[i,j] = K*a_i*b_j*4096*cost (in-place on out).
__global__ __launch_bounds__(256) void final_f32(float* __restrict__ out,
                                                 const float* __restrict__ avec,
                                                 const float* __restrict__ bvec,
                                                 const float* __restrict__ pos,
                                                 const float* __restrict__ alpha) {
    int bb = blockIdx.y;
    int i0 = blockIdx.x * 16;
    __shared__ float as_[16], ys[16], xs2[16];
    int t = threadIdx.x;
    if (t < 16) {
        int i = i0 + t;
        as_[t] = (i < NP1) ? avec[(size_t)bb * VSTR + i] : 0.f;
        if (i < NN) {
            ys[t]  = pos[((size_t)bb * NN + i) * 2 + 0];
            xs2[t] = pos[((size_t)bb * NN + i) * 2 + 1];
        } else {
            ys[t] = 1e9f; xs2[t] = 1e9f;
        }
    }
    __syncthreads();
    float E = __expf(alpha[0]);
    float* outb = out + (size_t)bb * NP1 * NP1;
    for (int j = t; j < NP1; j += 256) {
        float bj = bvec[(size_t)bb * VSTR + j];
        bool jin = (j < NN);
        float yj = 0.f, xj = 0.f;
        if (jin) {
            yj = pos[((size_t)bb * NN + j) * 2 + 0];
            xj = pos[((size_t)bb * NN + j) * 2 + 1];
        }
#pragma unroll 1
        for (int r = 0; r < 16; r++) {
            int i = i0 + r;
            if (i >= NP1) break;
            size_t idx = (size_t)i * NP1 + j;
            float v;
            if (i < NN && jin) {
                float Kv = outb[idx];
                bool c = (fabsf(ys[r] - yj) <= 0.1f) && (fabsf(xs2[r] - xj) <= 0.1f);
                v = c ? Kv * as_[r] * bj * 4096.0f : 0.0f;
            } else {
                v = E * as_[r] * bj * 4096.0f;
            }
            outb[idx] = v;
        }
    }
}

extern "C" void kernel_launch(void* const* d_in, const int* in_sizes, int n_in,
                              void* d_out, int out_size, void* d_ws, size_t ws_size,
                              hipStream_t stream) {
    const float* F     = (const float*)d_in[0];  // (B, D, N)
    const float* pos   = (const float*)d_in[1];  // (B, N, 2)
    const float* alpha = (const float*)d_in[3];  // (1,)
    float* out = (float*)d_out;
    float* ws  = (float*)d_ws;

    float* avec = ws;
    float* bvec = ws + BN * VSTR;
    float* sums = ws + 2 * BN * VSTR;                 // 41*BN floats (fallback path)
    int*   bar  = (int*)(sums + 41 * BN);             // BN x GRP arrival slots
    float* psum = (float*)(bar + BN * GRP);           // kept for layout stability
    unsigned char* K8  = (unsigned char*)(psum + 2 * BN * GRP);  // 33.5 MB fp8
    unsigned char* F16 = K8 + (size_t)BN * NN * NN;              // 8.4 MB bf16

    size_t need = (size_t)(2 * BN * VSTR + 41 * BN + 3 * BN * GRP) * 4
                + (size_t)BN * NN * NN + (size_t)BN * NN * DD * 2;
    bool fp8 = (ws_size >= need);

    hipLaunchKernelGGL(init_kernel, dim3(64), dim3(256), 0, stream, bvec, BN * VSTR,
                       sums, bar);

    if (fp8) {
        hipLaunchKernelGGL(f_to_bf16, dim3(NN / 64, DD / 64, BN), dim3(256), 0, stream,
                           F, F16);
        hipLaunchKernelGGL(build_k3, dim3(136, 1, BN), dim3(256), 0, stream, F16, K8);
        // Plain launch; co-residency guaranteed by LDS capacity (1 block/CU).
        // Fused final: sink writes d_out directly from the LDS K shard.
        hipLaunchKernelGGL(sink_persist, dim3(NBLK), dim3(1024), 0, stream,
                           K8, avec, bvec, bar, alpha, pos, out);
    } else {
        hipLaunchKernelGGL(build_k_f32, dim3(32, 32, BN), dim3(256), 0, stream, F, out);
        const float* xin = bvec;
        float* xout = avec;
        for (int p = 1; p <= 2 * NITER; p++) {
            hipLaunchKernelGGL(sink_pass_f32, dim3(NN / 16, BN), dim3(256), 0, stream,
                               out, xin, xout, sums + (p - 1) * BN, sums + p * BN, alpha);
            float* tmp = (float*)xin; xin = xout; xout = tmp;
        }
        hipLaunchKernelGGL(final_f32, dim3((NP1 + 15) / 16, BN), dim3(256), 0,
                           stream, out, avec, bvec, pos, alpha);
    }
}